// Round 5
// baseline (470.964 us; speedup 1.0000x reference)
//
#include <hip/hip_runtime.h>

#define B_    128
#define L_    512
#define H_    256
#define TGB_  128
#define S_    1023
#define BL_   (B_ * L_)     // 65536
#define SIXH  1536
#define FOURH 1024

typedef __bf16 bf16_t;
typedef bf16_t bf16x8 __attribute__((ext_vector_type(8)));
typedef float  f32x4  __attribute__((ext_vector_type(4)));

template<int P> struct IC { static constexpr int v = P; };

__device__ __forceinline__ unsigned short f2bf(float f) {
    union { float f; unsigned u; } v; v.f = f;
    unsigned u = v.u;
    unsigned r = u + 0x7FFFu + ((u >> 16) & 1u);   // round-to-nearest-even
    return (unsigned short)(r >> 16);
}
__device__ __forceinline__ float bf2f(unsigned short s) {
    union { unsigned u; float f; } v; v.u = ((unsigned)s) << 16;
    return v.f;
}

__device__ __forceinline__ void gload_lds16(const void* g, void* l) {
    __builtin_amdgcn_global_load_lds(
        (__attribute__((address_space(1))) void*)(void*)(g),
        (__attribute__((address_space(3))) void*)(l), 16, 0, 0);
}

// ---------------------------------------------------------------------------
// K0: transpose + f32->bf16 convert:  in (R x C) f32  ->  out (C x R) bf16
// ---------------------------------------------------------------------------
__global__ __launch_bounds__(256) void transpose_bf16_kernel(
    const float* __restrict__ in, unsigned short* __restrict__ out,
    int R, int C)
{
    __shared__ float tile[32][33];
    int rb = blockIdx.x * 32, cb = blockIdx.y * 32;
    int tx = threadIdx.x & 31, ty = threadIdx.x >> 5;   // 32 x 8
    #pragma unroll
    for (int d = 0; d < 32; d += 8)
        tile[ty + d][tx] = in[(size_t)(rb + ty + d) * C + cb + tx];
    __syncthreads();
    #pragma unroll
    for (int d = 0; d < 32; d += 8)
        out[(size_t)(cb + ty + d) * R + rb + tx] = f2bf(tile[tx][ty + d]);
}

// ---------------------------------------------------------------------------
// K1: gather 6 embeddings + LayerNorm over 1536 -> x_ln bf16 (BL x 1536)
// ---------------------------------------------------------------------------
__global__ __launch_bounds__(256) void embed_ln_kernel(
    const int* __restrict__ tok,  const int* __restrict__ ptok,
    const int* __restrict__ atok, const int* __restrict__ actok,
    const int* __restrict__ tgap, const int* __restrict__ gid,
    const float* __restrict__ ttab, const float* __restrict__ titab,
    const float* __restrict__ gtab, const float* __restrict__ gamma,
    const float* __restrict__ beta, unsigned short* __restrict__ xln)
{
    int e = blockIdx.x;
    int t = threadIdx.x;
    int i0 = tok[e], i1 = ptok[e], i2 = atok[e], i3 = actok[e];
    int i4 = tgap[e]; i4 = i4 < 0 ? 0 : (i4 > TGB_ ? TGB_ : i4);
    int i5 = gid[e];
    float v0 = ttab[(size_t)i0 * H_ + t];
    float v1 = ttab[(size_t)i1 * H_ + t];
    float v2 = ttab[(size_t)i2 * H_ + t];
    float v3 = ttab[(size_t)i3 * H_ + t];
    float v4 = titab[(size_t)i4 * H_ + t];
    float v5 = gtab[(size_t)i5 * H_ + t];
    float s  = v0 + v1 + v2 + v3 + v4 + v5;
    float sq = v0*v0 + v1*v1 + v2*v2 + v3*v3 + v4*v4 + v5*v5;
    #pragma unroll
    for (int off = 32; off > 0; off >>= 1) {
        s  += __shfl_down(s,  off);
        sq += __shfl_down(sq, off);
    }
    __shared__ float red[8];
    int lane = t & 63, w = t >> 6;
    if (lane == 0) { red[w] = s; red[4 + w] = sq; }
    __syncthreads();
    float stot  = red[0] + red[1] + red[2] + red[3];
    float sqtot = red[4] + red[5] + red[6] + red[7];
    float mean = stot * (1.0f / 1536.0f);
    float var  = sqtot * (1.0f / 1536.0f) - mean * mean;
    float rstd = rsqrtf(var + 1e-5f);
    float vv[6] = { v0, v1, v2, v3, v4, v5 };
    unsigned short* orow = xln + (size_t)e * SIXH;
    #pragma unroll
    for (int k = 0; k < 6; ++k) {
        int idx = k * H_ + t;
        float y = (vv[k] - mean) * rstd * gamma[idx] + beta[idx];
        orow[idx] = f2bf(y);
    }
}

// ---------------------------------------------------------------------------
// K2: pair-fused 8-phase 256x256 bf16 MFMA GEMM.
// C(MxN) = epi(A(MxK) @ Bt(NxK)^T + bias), M = 65536.
// 512 threads = 8 waves (2m x 4n), per-wave C = 128x64, 16x16x32 MFMA.
// LDS 128 KiB: 2 bufs (kt parity) x { A[2 kh][256r][32c], B[...] }.
// Pair structure: per pair, 12 ds_read_b128 (4 B + 8 A) then 2x16 MFMA
// clusters (compiler emits counted lgkmcnt(4)/lgkmcnt(0) between) --
// second cluster's read latency hides under first cluster's MFMA issue.
// 4 barriers/iteration (pair boundaries); counted vmcnt(4) at pairs 1,3
// only (never drains mid-loop). Staging fully compile-time: 4 base
// pointers advanced +128/iter; unit offsets {96,128,160,192} fold to imm.
// XOR swizzle (verified 0-conflict) on both global source and ds_read.
// EPI 0: silu   EPI 1: plain bias add
// ---------------------------------------------------------------------------
template<int N, int K, int NTN, int EPI>
__global__ __launch_bounds__(512, 2) void gemm256_kernel(
    const unsigned short* __restrict__ A,
    const unsigned short* __restrict__ Bt,
    const float* __restrict__ bias,
    unsigned short* __restrict__ C)
{
    constexpr int NT = K / 64;        // K-tiles
    constexpr int IT = NT / 2;        // 2 K-tiles per iteration
    constexpr int NBLK = 256 * NTN;   // (M/256) * NTN
    constexpr int CHUNK = NBLK / 8;
    extern __shared__ __align__(16) unsigned short lds[];   // 65536 shorts

    const int bid = blockIdx.x;
    const int wid = (bid & 7) * CHUNK + (bid >> 3);   // XCD-bijective swizzle
    const int mt  = wid / NTN;
    const int m0  = mt * 256;
    const int n0  = (wid - mt * NTN) * 256;

    const int t = threadIdx.x;
    const int w = t >> 6, l = t & 63;
    const int wm = w >> 2, wn = w & 3;
    const int r16 = l & 15, ql = l >> 4;

    // staging sources (pre-swizzled chunk group), advanced +128 shorts/iter
    const int sg = (t & 3) ^ ((t >> 3) & 3);
    const unsigned short* As0 = A  + (size_t)(m0 + (t >> 2)) * K + sg * 8;
    const unsigned short* As1 = As0 + (size_t)128 * K;
    const unsigned short* Bs0 = Bt + (size_t)(n0 + (t >> 2)) * K + sg * 8;
    const unsigned short* Bs1 = Bs0 + (size_t)128 * K;
    unsigned short* ldsb = lds + w * 512;              // wave-uniform dest base

    // fragment read bases (shorts); per-read imm = KK*8192 + mi*512 (+2048 MH)
    const int fr = (ql ^ ((r16 >> 1) & 3)) * 8;
    const unsigned short* la0 = lds + (wm * 128 + r16) * 32 + fr;          // buf0 A
    const unsigned short* la1 = la0 + 32768;                                // buf1 A
    const unsigned short* lb0 = lds + 16384 + (wn * 64 + r16) * 32 + fr;   // buf0 B
    const unsigned short* lb1 = lb0 + 32768;                                // buf1 B

    f32x4 acc[8][4];
    #pragma unroll
    for (int i = 0; i < 8; ++i)
        #pragma unroll
        for (int j = 0; j < 4; ++j) acc[i][j] = (f32x4)0.0f;

    // stage one unit (2 gloads): dofs/gofs in shorts, compile-time at calls
    auto ST2 = [&](const unsigned short* s0, const unsigned short* s1,
                   int dofs, int gofs) {
        gload_lds16(s0 + gofs, ldsb + dofs);
        gload_lds16(s1 + gofs, ldsb + dofs + 4096);
    };

    // prologue: units 0..5 (kt0 full, kt1 kh0)
    ST2(As0, As1, 0,             0);    // u0 buf0 A kh0
    ST2(Bs0, Bs1, 16384,         0);    // u1 buf0 B kh0
    ST2(As0, As1, 8192,          32);   // u2 buf0 A kh1
    ST2(Bs0, Bs1, 24576,         32);   // u3 buf0 B kh1
    ST2(As0, As1, 32768,         64);   // u4 buf1 A kh0
    ST2(Bs0, Bs1, 49152,         64);   // u5 buf1 B kh0
    asm volatile("s_waitcnt vmcnt(4)\ns_barrier" ::: "memory");

    // pair PR: BUF=PR>>1, KK=PR&1; reads 4 B + 8 A; 2 MFMA clusters
    auto pair = [&](auto pc, bool last) {
        constexpr int PR  = decltype(pc)::v;
        constexpr int BUF = PR >> 1;
        constexpr int KKo = (PR & 1) * 8192;
        const unsigned short* ab = (BUF ? la1 : la0) + KKo;
        const unsigned short* bb = (BUF ? lb1 : lb0) + KKo;
        bf16x8 bq[4], a0q[4], a1q[4];
        #pragma unroll
        for (int i = 0; i < 4; ++i) bq[i]  = *(const bf16x8*)(bb + i * 512);
        #pragma unroll
        for (int i = 0; i < 4; ++i) a0q[i] = *(const bf16x8*)(ab + i * 512);
        #pragma unroll
        for (int i = 0; i < 4; ++i) a1q[i] = *(const bf16x8*)(ab + 2048 + i * 512);
        // staging (unit constants; kt guard is just `last`)
        if constexpr (PR == 0) {        // u6,u7: buf1 kh1 (kt=2it+1) - always
            ST2(As0, As1, 40960, 96); ST2(Bs0, Bs1, 57344, 96);
        } else if constexpr (PR == 1) { // u8,u9: buf0 kh0 (kt=2it+2)
            if (!last) { ST2(As0, As1, 0, 128); ST2(Bs0, Bs1, 16384, 128); }
        } else if constexpr (PR == 2) { // u10,u11: buf0 kh1
            if (!last) { ST2(As0, As1, 8192, 160); ST2(Bs0, Bs1, 24576, 160); }
        } else {                        // u12,u13: buf1 kh0 (kt=2it+3)
            if (!last) { ST2(As0, As1, 32768, 192); ST2(Bs0, Bs1, 49152, 192); }
        }
        __builtin_amdgcn_s_setprio(1);
        #pragma unroll
        for (int mm = 0; mm < 4; ++mm)
            #pragma unroll
            for (int nn = 0; nn < 4; ++nn)
                acc[mm][nn] = __builtin_amdgcn_mfma_f32_16x16x32_bf16(
                    a0q[mm], bq[nn], acc[mm][nn], 0, 0, 0);
        #pragma unroll
        for (int mm = 0; mm < 4; ++mm)
            #pragma unroll
            for (int nn = 0; nn < 4; ++nn)
                acc[4 + mm][nn] = __builtin_amdgcn_mfma_f32_16x16x32_bf16(
                    a1q[mm], bq[nn], acc[4 + mm][nn], 0, 0, 0);
        __builtin_amdgcn_s_setprio(0);
        if constexpr (PR == 1) {
            if (last) asm volatile("s_waitcnt vmcnt(0)\ns_barrier" ::: "memory");
            else      asm volatile("s_waitcnt vmcnt(4)\ns_barrier" ::: "memory");
        } else if constexpr (PR == 3) {
            if (!last) asm volatile("s_waitcnt vmcnt(4)\ns_barrier" ::: "memory");
        } else {
            asm volatile("s_barrier" ::: "memory");
        }
    };

    for (int it = 0; it < IT; ++it) {
        const bool last = (it == IT - 1);
        pair(IC<0>{}, last);
        pair(IC<1>{}, last);
        pair(IC<2>{}, last);
        pair(IC<3>{}, last);
        As0 += 128; As1 += 128; Bs0 += 128; Bs1 += 128;
    }

    // epilogue
    #pragma unroll
    for (int mi = 0; mi < 8; ++mi) {
        #pragma unroll
        for (int ni = 0; ni < 4; ++ni) {
            int col = n0 + wn * 64 + ni * 16 + r16;
            float bv = bias[col];
            #pragma unroll
            for (int j = 0; j < 4; ++j) {
                int row = m0 + wm * 128 + mi * 16 + ql * 4 + j;
                float v = acc[mi][ni][j] + bv;
                if (EPI == 0) v = v / (1.0f + __expf(-v));   // silu
                C[(size_t)row * N + col] = f2bf(v);
            }
        }
    }
}

// ---------------------------------------------------------------------------
// K3: per-batch boundary + exclusive cumsum + inverse index map
// ---------------------------------------------------------------------------
__global__ __launch_bounds__(512) void scan_scatter_kernel(
    const int* __restrict__ gid, const int* __restrict__ lengths,
    int* __restrict__ idx_map, int* __restrict__ shiftb)
{
    int b = blockIdx.x, i = threadIdx.x;
    int len = lengths[b];
    int g  = gid[b * L_ + i];
    int gn = (i < L_ - 1) ? gid[b * L_ + i + 1] : g;
    int bnd = (i < len - 1 && g != gn) ? 1 : 0;
    __shared__ int sc[512];
    sc[i] = bnd;
    __syncthreads();
    for (int off = 1; off < 512; off <<= 1) {
        int v = (i >= off) ? sc[i - off] : 0;
        __syncthreads();
        sc[i] += v;
        __syncthreads();
    }
    int incl  = sc[i];
    int total = sc[511];
    int ex = incl - bnd;
    int M = len + total;
    int shift = S_ - M;          // always >= 0
    for (int s = i; s < S_; s += 512) idx_map[b * S_ + s] = -1;
    __syncthreads();
    if (i < len) {
        int p = shift + i + ex;
        idx_map[b * S_ + p] = i;
        if (bnd) idx_map[b * S_ + p + 1] = -2;
    }
    if (i == 0) shiftb[b] = shift;
}

// ---------------------------------------------------------------------------
// K4: final fill: merged[b][s][:] and mask[b][s]
// ---------------------------------------------------------------------------
__global__ __launch_bounds__(256) void out_kernel(
    const int* __restrict__ idx_map, const int* __restrict__ shiftb,
    const unsigned short* __restrict__ event,
    const float* __restrict__ pos_table, const float* __restrict__ sep,
    float* __restrict__ out)
{
    int s = blockIdx.x, b = blockIdx.y, t = threadIdx.x;
    int shift = shiftb[b];
    float val = 0.0f;
    if (s >= shift) {
        int idx = idx_map[b * S_ + s];
        float add = 0.0f;
        if (idx >= 0)       add = bf2f(event[((size_t)b * L_ + idx) * H_ + t]);
        else if (idx == -2) add = sep[t];
        val = pos_table[(size_t)s * H_ + t] + add;
    }
    out[((size_t)b * S_ + s) * H_ + t] = val;
    if (t == 0)
        out[(size_t)B_ * S_ * H_ + (size_t)b * S_ + s] = (s >= shift) ? 1.0f : 0.0f;
}

// ---------------------------------------------------------------------------
extern "C" void kernel_launch(void* const* d_in, const int* in_sizes, int n_in,
                              void* d_out, int out_size, void* d_ws, size_t ws_size,
                              hipStream_t stream)
{
    const int*   tok   = (const int*)d_in[0];
    const int*   ptok  = (const int*)d_in[1];
    const int*   atok  = (const int*)d_in[2];
    const int*   actok = (const int*)d_in[3];
    const int*   tgap  = (const int*)d_in[4];
    const int*   gid   = (const int*)d_in[5];
    const int*   lens  = (const int*)d_in[6];
    const float* ttab  = (const float*)d_in[7];
    const float* titab = (const float*)d_in[8];
    const float* gtab  = (const float*)d_in[9];
    const float* post  = (const float*)d_in[10];
    const float* sep   = (const float*)d_in[11];
    const float* gamma = (const float*)d_in[12];
    const float* beta  = (const float*)d_in[13];
    const float* W1    = (const float*)d_in[14];
    const float* b1    = (const float*)d_in[15];
    const float* W2    = (const float*)d_in[16];
    const float* b2    = (const float*)d_in[17];

    unsigned short* xln  = (unsigned short*)d_ws;                 // BL*1536 bf16
    unsigned short* hbuf = xln  + (size_t)BL_ * SIXH;             // BL*1024 bf16
    unsigned short* evb  = hbuf + (size_t)BL_ * FOURH;            // BL*256  bf16
    unsigned short* W1T  = evb  + (size_t)BL_ * H_;               // 1024*1536 bf16
    unsigned short* W2T  = W1T  + (size_t)FOURH * SIXH;           // 256*1024 bf16
    int* idx_map = (int*)(W2T + (size_t)H_ * FOURH);              // B*S int
    int* shiftb  = idx_map + B_ * S_;                             // B int
    float* out   = (float*)d_out;

    constexpr int LDS_BYTES = 2 * 32768 * 2;                      // 131072
    (void)hipFuncSetAttribute((const void*)&gemm256_kernel<FOURH, SIXH, 4, 0>,
                              hipFuncAttributeMaxDynamicSharedMemorySize, LDS_BYTES);
    (void)hipFuncSetAttribute((const void*)&gemm256_kernel<H_, FOURH, 1, 1>,
                              hipFuncAttributeMaxDynamicSharedMemorySize, LDS_BYTES);

    // weight transposes (f32 -> bf16, NxK layout for MFMA B-operand)
    transpose_bf16_kernel<<<dim3(SIXH / 32, FOURH / 32), 256, 0, stream>>>(W1, W1T, SIXH, FOURH);
    transpose_bf16_kernel<<<dim3(FOURH / 32, H_ / 32),   256, 0, stream>>>(W2, W2T, FOURH, H_);

    // embed + layernorm
    embed_ln_kernel<<<BL_, 256, 0, stream>>>(tok, ptok, atok, actok, tgap, gid,
                                             ttab, titab, gtab, gamma, beta, xln);

    // MLP (pair-fused 8-phase 256^2 GEMMs)
    gemm256_kernel<FOURH, SIXH, 4, 0><<<(BL_ / 256) * 4, 512, LDS_BYTES, stream>>>(xln, W1T, b1, hbuf);
    gemm256_kernel<H_, FOURH, 1, 1><<<(BL_ / 256) * 1, 512, LDS_BYTES, stream>>>(hbuf, W2T, b2, evb);

    // scan + inverse scatter map
    scan_scatter_kernel<<<B_, 512, 0, stream>>>(gid, lens, idx_map, shiftb);

    // final output
    out_kernel<<<dim3(S_, B_), 256, 0, stream>>>(idx_map, shiftb, evb, post, sep, out);
}

// Round 6
// 456.963 us; speedup vs baseline: 1.0306x; 1.0306x over previous
//
#include <hip/hip_runtime.h>

#define B_    128
#define L_    512
#define H_    256
#define TGB_  128
#define S_    1023
#define BL_   (B_ * L_)     // 65536
#define SIXH  1536
#define FOURH 1024

typedef __bf16 bf16_t;
typedef bf16_t bf16x8 __attribute__((ext_vector_type(8)));
typedef float  f32x4  __attribute__((ext_vector_type(4)));

template<int P> struct IC { static constexpr int v = P; };

__device__ __forceinline__ unsigned short f2bf(float f) {
    union { float f; unsigned u; } v; v.f = f;
    unsigned u = v.u;
    unsigned r = u + 0x7FFFu + ((u >> 16) & 1u);   // round-to-nearest-even
    return (unsigned short)(r >> 16);
}
__device__ __forceinline__ float bf2f(unsigned short s) {
    union { unsigned u; float f; } v; v.u = ((unsigned)s) << 16;
    return v.f;
}

__device__ __forceinline__ void gload_lds16(const void* g, void* l) {
    __builtin_amdgcn_global_load_lds(
        (__attribute__((address_space(1))) void*)(void*)(g),
        (__attribute__((address_space(3))) void*)(l), 16, 0, 0);
}

// ---------------------------------------------------------------------------
// K0: transpose + f32->bf16 convert:  in (R x C) f32  ->  out (C x R) bf16
// ---------------------------------------------------------------------------
__global__ __launch_bounds__(256) void transpose_bf16_kernel(
    const float* __restrict__ in, unsigned short* __restrict__ out,
    int R, int C)
{
    __shared__ float tile[32][33];
    int rb = blockIdx.x * 32, cb = blockIdx.y * 32;
    int tx = threadIdx.x & 31, ty = threadIdx.x >> 5;   // 32 x 8
    #pragma unroll
    for (int d = 0; d < 32; d += 8)
        tile[ty + d][tx] = in[(size_t)(rb + ty + d) * C + cb + tx];
    __syncthreads();
    #pragma unroll
    for (int d = 0; d < 32; d += 8)
        out[(size_t)(cb + ty + d) * R + rb + tx] = f2bf(tile[tx][ty + d]);
}

// ---------------------------------------------------------------------------
// K1: gather 6 embeddings + LayerNorm over 1536 -> x_ln bf16 (BL x 1536)
// ---------------------------------------------------------------------------
__global__ __launch_bounds__(256) void embed_ln_kernel(
    const int* __restrict__ tok,  const int* __restrict__ ptok,
    const int* __restrict__ atok, const int* __restrict__ actok,
    const int* __restrict__ tgap, const int* __restrict__ gid,
    const float* __restrict__ ttab, const float* __restrict__ titab,
    const float* __restrict__ gtab, const float* __restrict__ gamma,
    const float* __restrict__ beta, unsigned short* __restrict__ xln)
{
    int e = blockIdx.x;
    int t = threadIdx.x;
    int i0 = tok[e], i1 = ptok[e], i2 = atok[e], i3 = actok[e];
    int i4 = tgap[e]; i4 = i4 < 0 ? 0 : (i4 > TGB_ ? TGB_ : i4);
    int i5 = gid[e];
    float v0 = ttab[(size_t)i0 * H_ + t];
    float v1 = ttab[(size_t)i1 * H_ + t];
    float v2 = ttab[(size_t)i2 * H_ + t];
    float v3 = ttab[(size_t)i3 * H_ + t];
    float v4 = titab[(size_t)i4 * H_ + t];
    float v5 = gtab[(size_t)i5 * H_ + t];
    float s  = v0 + v1 + v2 + v3 + v4 + v5;
    float sq = v0*v0 + v1*v1 + v2*v2 + v3*v3 + v4*v4 + v5*v5;
    #pragma unroll
    for (int off = 32; off > 0; off >>= 1) {
        s  += __shfl_down(s,  off);
        sq += __shfl_down(sq, off);
    }
    __shared__ float red[8];
    int lane = t & 63, w = t >> 6;
    if (lane == 0) { red[w] = s; red[4 + w] = sq; }
    __syncthreads();
    float stot  = red[0] + red[1] + red[2] + red[3];
    float sqtot = red[4] + red[5] + red[6] + red[7];
    float mean = stot * (1.0f / 1536.0f);
    float var  = sqtot * (1.0f / 1536.0f) - mean * mean;
    float rstd = rsqrtf(var + 1e-5f);
    float vv[6] = { v0, v1, v2, v3, v4, v5 };
    unsigned short* orow = xln + (size_t)e * SIXH;
    #pragma unroll
    for (int k = 0; k < 6; ++k) {
        int idx = k * H_ + t;
        float y = (vv[k] - mean) * rstd * gamma[idx] + beta[idx];
        orow[idx] = f2bf(y);
    }
}

// ---------------------------------------------------------------------------
// K2: 8-phase 256x256 bf16 MFMA GEMM (r4 structure + compile-time staging).
// C(MxN) = epi(A(MxK) @ Bt(NxK)^T + bias), M = 65536.
// 512 threads = 8 waves (2m x 4n), per-wave C = 128x64, 16x16x32 MFMA.
// LDS 128 KiB: 2 bufs (kt parity) x { A[2 kh][256r][32c], B[...] }.
// Per phase: {ds_read frags; stage 1 unit (2 gload_lds, compile-time
// dofs/gofs); s_barrier; setprio(1); 16 MFMA (compiler emits counted
// lgkmcnt); setprio(0); end-sync}. vmcnt(4) at P3/P7 only (never drains
// mid-loop). Unit->phase mapping identical to round-4 (RAW/WAR verified).
// XOR swizzle (measured 0-conflict) on both global source and ds_read.
// EPI 0: silu   EPI 1: plain bias add
// ---------------------------------------------------------------------------
template<int N, int K, int NTN, int EPI>
__global__ __launch_bounds__(512, 2) void gemm256_kernel(
    const unsigned short* __restrict__ A,
    const unsigned short* __restrict__ Bt,
    const float* __restrict__ bias,
    unsigned short* __restrict__ C)
{
    constexpr int NT = K / 64;        // K-tiles
    constexpr int IT = NT / 2;        // 2 K-tiles per iteration
    constexpr int NBLK = 256 * NTN;   // (M/256) * NTN
    constexpr int CHUNK = NBLK / 8;
    extern __shared__ __align__(16) unsigned short lds[];   // 65536 shorts

    const int bid = blockIdx.x;
    const int wid = (bid & 7) * CHUNK + (bid >> 3);   // XCD-bijective swizzle
    const int mt  = wid / NTN;
    const int m0  = mt * 256;
    const int n0  = (wid - mt * NTN) * 256;

    const int t = threadIdx.x;
    const int w = t >> 6, l = t & 63;
    const int wm = w >> 2, wn = w & 3;
    const int r16 = l & 15, ql = l >> 4;

    // staging sources (pre-swizzled chunk group), advanced +128 shorts/iter
    const int sg = (t & 3) ^ ((t >> 3) & 3);
    const unsigned short* As0 = A  + (size_t)(m0 + (t >> 2)) * K + sg * 8;
    const unsigned short* As1 = As0 + (size_t)128 * K;
    const unsigned short* Bs0 = Bt + (size_t)(n0 + (t >> 2)) * K + sg * 8;
    const unsigned short* Bs1 = Bs0 + (size_t)128 * K;
    unsigned short* ldsb = lds + w * 512;              // wave-uniform dest base

    // fragment read bases (shorts)
    const int fr = (ql ^ ((r16 >> 1) & 3)) * 8;
    const unsigned short* la0 = lds + (wm * 128 + r16) * 32 + fr;          // buf0 A
    const unsigned short* la1 = la0 + 32768;                                // buf1 A
    const unsigned short* lb0 = lds + 16384 + (wn * 64 + r16) * 32 + fr;   // buf0 B
    const unsigned short* lb1 = lb0 + 32768;                                // buf1 B

    f32x4 acc[8][4];
    #pragma unroll
    for (int i = 0; i < 8; ++i)
        #pragma unroll
        for (int j = 0; j < 4; ++j) acc[i][j] = (f32x4)0.0f;

    // stage one unit (2 gloads): dofs/gofs compile-time at all call sites
    auto ST2 = [&](const unsigned short* s0, const unsigned short* s1,
                   int dofs, int gofs) {
        gload_lds16(s0 + gofs, ldsb + dofs);
        gload_lds16(s1 + gofs, ldsb + dofs + 4096);
    };

    // prologue: units 0..5 (kt0 full, kt1 kh0)
    ST2(As0, As1, 0,     0);    // u0 buf0 A kh0
    ST2(Bs0, Bs1, 16384, 0);    // u1 buf0 B kh0
    ST2(As0, As1, 8192,  32);   // u2 buf0 A kh1
    ST2(Bs0, Bs1, 24576, 32);   // u3 buf0 B kh1
    ST2(As0, As1, 32768, 64);   // u4 buf1 A kh0
    ST2(Bs0, Bs1, 49152, 64);   // u5 buf1 B kh0
    asm volatile("s_waitcnt vmcnt(4)\ns_barrier" ::: "memory");

    bf16x8 bq[4];

    // phase P: BUF=P>>2, KK=(P&3)>>1, MH=P&1; 8 A-reads.. 4 A + (MH==0: 4 B)
    auto phase = [&](auto pc, bool last) {
        constexpr int P   = decltype(pc)::v;
        constexpr int BUF = P >> 2;
        constexpr int KK  = (P & 3) >> 1;
        constexpr int MH  = P & 1;
        const unsigned short* ab = (BUF ? la1 : la0) + KK * 8192 + MH * 2048;
        bf16x8 aq[4];
        if constexpr (MH == 0) {
            const unsigned short* bb = (BUF ? lb1 : lb0) + KK * 8192;
            bq[0] = *(const bf16x8*)(bb);
            bq[1] = *(const bf16x8*)(bb + 512);
            bq[2] = *(const bf16x8*)(bb + 1024);
            bq[3] = *(const bf16x8*)(bb + 1536);
        }
        aq[0] = *(const bf16x8*)(ab);
        aq[1] = *(const bf16x8*)(ab + 512);
        aq[2] = *(const bf16x8*)(ab + 1024);
        aq[3] = *(const bf16x8*)(ab + 1536);
        // staging: unit u = 8it+6+P (same mapping as round 4, all imm)
        if constexpr (P == 0)      {            ST2(As0, As1, 40960, 96);  }
        else if constexpr (P == 1) {            ST2(Bs0, Bs1, 57344, 96);  }
        else if constexpr (P == 2) { if (!last) ST2(As0, As1, 0,     128); }
        else if constexpr (P == 3) { if (!last) ST2(Bs0, Bs1, 16384, 128); }
        else if constexpr (P == 4) { if (!last) ST2(As0, As1, 8192,  160); }
        else if constexpr (P == 5) { if (!last) ST2(Bs0, Bs1, 24576, 160); }
        else if constexpr (P == 6) { if (!last) ST2(As0, As1, 32768, 192); }
        else                       { if (!last) ST2(Bs0, Bs1, 49152, 192); }
        asm volatile("s_barrier" ::: "memory");
        __builtin_amdgcn_s_setprio(1);
        #pragma unroll
        for (int mm = 0; mm < 4; ++mm)
            #pragma unroll
            for (int nn = 0; nn < 4; ++nn)
                acc[MH * 4 + mm][nn] = __builtin_amdgcn_mfma_f32_16x16x32_bf16(
                    aq[mm], bq[nn], acc[MH * 4 + mm][nn], 0, 0, 0);
        __builtin_amdgcn_s_setprio(0);
        if constexpr (P == 3) {
            if (last) asm volatile("s_waitcnt vmcnt(0)\ns_barrier" ::: "memory");
            else      asm volatile("s_waitcnt vmcnt(4)\ns_barrier" ::: "memory");
        } else if constexpr (P == 7) {
            if (!last) asm volatile("s_waitcnt vmcnt(4)\ns_barrier" ::: "memory");
        } else {
            asm volatile("s_barrier" ::: "memory");
        }
    };

    for (int it = 0; it < IT; ++it) {
        const bool last = (it == IT - 1);
        phase(IC<0>{}, last);
        phase(IC<1>{}, last);
        phase(IC<2>{}, last);
        phase(IC<3>{}, last);
        phase(IC<4>{}, last);
        phase(IC<5>{}, last);
        phase(IC<6>{}, last);
        phase(IC<7>{}, last);
        As0 += 128; As1 += 128; Bs0 += 128; Bs1 += 128;
    }

    // epilogue
    #pragma unroll
    for (int mi = 0; mi < 8; ++mi) {
        #pragma unroll
        for (int ni = 0; ni < 4; ++ni) {
            int col = n0 + wn * 64 + ni * 16 + r16;
            float bv = bias[col];
            #pragma unroll
            for (int j = 0; j < 4; ++j) {
                int row = m0 + wm * 128 + mi * 16 + ql * 4 + j;
                float v = acc[mi][ni][j] + bv;
                if (EPI == 0) v = v / (1.0f + __expf(-v));   // silu
                C[(size_t)row * N + col] = f2bf(v);
            }
        }
    }
}

// ---------------------------------------------------------------------------
// K3: per-batch boundary + exclusive cumsum + inverse index map
// ---------------------------------------------------------------------------
__global__ __launch_bounds__(512) void scan_scatter_kernel(
    const int* __restrict__ gid, const int* __restrict__ lengths,
    int* __restrict__ idx_map, int* __restrict__ shiftb)
{
    int b = blockIdx.x, i = threadIdx.x;
    int len = lengths[b];
    int g  = gid[b * L_ + i];
    int gn = (i < L_ - 1) ? gid[b * L_ + i + 1] : g;
    int bnd = (i < len - 1 && g != gn) ? 1 : 0;
    __shared__ int sc[512];
    sc[i] = bnd;
    __syncthreads();
    for (int off = 1; off < 512; off <<= 1) {
        int v = (i >= off) ? sc[i - off] : 0;
        __syncthreads();
        sc[i] += v;
        __syncthreads();
    }
    int incl  = sc[i];
    int total = sc[511];
    int ex = incl - bnd;
    int M = len + total;
    int shift = S_ - M;          // always >= 0
    for (int s = i; s < S_; s += 512) idx_map[b * S_ + s] = -1;
    __syncthreads();
    if (i < len) {
        int p = shift + i + ex;
        idx_map[b * S_ + p] = i;
        if (bnd) idx_map[b * S_ + p + 1] = -2;
    }
    if (i == 0) shiftb[b] = shift;
}

// ---------------------------------------------------------------------------
// K4: final fill: merged[b][s][:] and mask[b][s]
// ---------------------------------------------------------------------------
__global__ __launch_bounds__(256) void out_kernel(
    const int* __restrict__ idx_map, const int* __restrict__ shiftb,
    const unsigned short* __restrict__ event,
    const float* __restrict__ pos_table, const float* __restrict__ sep,
    float* __restrict__ out)
{
    int s = blockIdx.x, b = blockIdx.y, t = threadIdx.x;
    int shift = shiftb[b];
    float val = 0.0f;
    if (s >= shift) {
        int idx = idx_map[b * S_ + s];
        float add = 0.0f;
        if (idx >= 0)       add = bf2f(event[((size_t)b * L_ + idx) * H_ + t]);
        else if (idx == -2) add = sep[t];
        val = pos_table[(size_t)s * H_ + t] + add;
    }
    out[((size_t)b * S_ + s) * H_ + t] = val;
    if (t == 0)
        out[(size_t)B_ * S_ * H_ + (size_t)b * S_ + s] = (s >= shift) ? 1.0f : 0.0f;
}

// ---------------------------------------------------------------------------
extern "C" void kernel_launch(void* const* d_in, const int* in_sizes, int n_in,
                              void* d_out, int out_size, void* d_ws, size_t ws_size,
                              hipStream_t stream)
{
    const int*   tok   = (const int*)d_in[0];
    const int*   ptok  = (const int*)d_in[1];
    const int*   atok  = (const int*)d_in[2];
    const int*   actok = (const int*)d_in[3];
    const int*   tgap  = (const int*)d_in[4];
    const int*   gid   = (const int*)d_in[5];
    const int*   lens  = (const int*)d_in[6];
    const float* ttab  = (const float*)d_in[7];
    const float* titab = (const float*)d_in[8];
    const float* gtab  = (const float*)d_in[9];
    const float* post  = (const float*)d_in[10];
    const float* sep   = (const float*)d_in[11];
    const float* gamma = (const float*)d_in[12];
    const float* beta  = (const float*)d_in[13];
    const float* W1    = (const float*)d_in[14];
    const float* b1    = (const float*)d_in[15];
    const float* W2    = (const float*)d_in[16];
    const float* b2    = (const float*)d_in[17];

    unsigned short* xln  = (unsigned short*)d_ws;                 // BL*1536 bf16
    unsigned short* hbuf = xln  + (size_t)BL_ * SIXH;             // BL*1024 bf16
    unsigned short* evb  = hbuf + (size_t)BL_ * FOURH;            // BL*256  bf16
    unsigned short* W1T  = evb  + (size_t)BL_ * H_;               // 1024*1536 bf16
    unsigned short* W2T  = W1T  + (size_t)FOURH * SIXH;           // 256*1024 bf16
    int* idx_map = (int*)(W2T + (size_t)H_ * FOURH);              // B*S int
    int* shiftb  = idx_map + B_ * S_;                             // B int
    float* out   = (float*)d_out;

    constexpr int LDS_BYTES = 2 * 32768 * 2;                      // 131072
    (void)hipFuncSetAttribute((const void*)&gemm256_kernel<FOURH, SIXH, 4, 0>,
                              hipFuncAttributeMaxDynamicSharedMemorySize, LDS_BYTES);
    (void)hipFuncSetAttribute((const void*)&gemm256_kernel<H_, FOURH, 1, 1>,
                              hipFuncAttributeMaxDynamicSharedMemorySize, LDS_BYTES);

    // weight transposes (f32 -> bf16, NxK layout for MFMA B-operand)
    transpose_bf16_kernel<<<dim3(SIXH / 32, FOURH / 32), 256, 0, stream>>>(W1, W1T, SIXH, FOURH);
    transpose_bf16_kernel<<<dim3(FOURH / 32, H_ / 32),   256, 0, stream>>>(W2, W2T, FOURH, H_);

    // embed + layernorm
    embed_ln_kernel<<<BL_, 256, 0, stream>>>(tok, ptok, atok, actok, tgap, gid,
                                             ttab, titab, gtab, gamma, beta, xln);

    // MLP (8-phase 256^2 GEMMs)
    gemm256_kernel<FOURH, SIXH, 4, 0><<<(BL_ / 256) * 4, 512, LDS_BYTES, stream>>>(xln, W1T, b1, hbuf);
    gemm256_kernel<H_, FOURH, 1, 1><<<(BL_ / 256) * 1, 512, LDS_BYTES, stream>>>(hbuf, W2T, b2, evb);

    // scan + inverse scatter map
    scan_scatter_kernel<<<B_, 512, 0, stream>>>(gid, lens, idx_map, shiftb);

    // final output
    out_kernel<<<dim3(S_, B_), 256, 0, stream>>>(idx_map, shiftb, evb, post, sep, out);
}

// Round 7
// 447.039 us; speedup vs baseline: 1.0535x; 1.0222x over previous
//
#include <hip/hip_runtime.h>

#define B_    128
#define L_    512
#define H_    256
#define TGB_  128
#define S_    1023
#define BL_   (B_ * L_)     // 65536
#define SIXH  1536
#define FOURH 1024

typedef __bf16 bf16_t;
typedef bf16_t bf16x8 __attribute__((ext_vector_type(8)));
typedef float  f32x4  __attribute__((ext_vector_type(4)));

template<int P> struct IC { static constexpr int v = P; };

__device__ __forceinline__ unsigned short f2bf(float f) {
    union { float f; unsigned u; } v; v.f = f;
    unsigned u = v.u;
    unsigned r = u + 0x7FFFu + ((u >> 16) & 1u);   // round-to-nearest-even
    return (unsigned short)(r >> 16);
}
__device__ __forceinline__ float bf2f(unsigned short s) {
    union { unsigned u; float f; } v; v.u = ((unsigned)s) << 16;
    return v.f;
}

__device__ __forceinline__ void gload_lds16(const void* g, void* l) {
    __builtin_amdgcn_global_load_lds(
        (__attribute__((address_space(1))) void*)(void*)(g),
        (__attribute__((address_space(3))) void*)(l), 16, 0, 0);
}

// ---------------------------------------------------------------------------
// K0: transpose + f32->bf16 convert:  in (R x C) f32  ->  out (C x R) bf16
// ---------------------------------------------------------------------------
__global__ __launch_bounds__(256) void transpose_bf16_kernel(
    const float* __restrict__ in, unsigned short* __restrict__ out,
    int R, int C)
{
    __shared__ float tile[32][33];
    int rb = blockIdx.x * 32, cb = blockIdx.y * 32;
    int tx = threadIdx.x & 31, ty = threadIdx.x >> 5;   // 32 x 8
    #pragma unroll
    for (int d = 0; d < 32; d += 8)
        tile[ty + d][tx] = in[(size_t)(rb + ty + d) * C + cb + tx];
    __syncthreads();
    #pragma unroll
    for (int d = 0; d < 32; d += 8)
        out[(size_t)(cb + ty + d) * R + rb + tx] = f2bf(tile[tx][ty + d]);
}

// ---------------------------------------------------------------------------
// K1: gather 6 embeddings + LayerNorm over 1536 -> x_ln bf16 (BL x 1536)
// ---------------------------------------------------------------------------
__global__ __launch_bounds__(256) void embed_ln_kernel(
    const int* __restrict__ tok,  const int* __restrict__ ptok,
    const int* __restrict__ atok, const int* __restrict__ actok,
    const int* __restrict__ tgap, const int* __restrict__ gid,
    const float* __restrict__ ttab, const float* __restrict__ titab,
    const float* __restrict__ gtab, const float* __restrict__ gamma,
    const float* __restrict__ beta, unsigned short* __restrict__ xln)
{
    int e = blockIdx.x;
    int t = threadIdx.x;
    int i0 = tok[e], i1 = ptok[e], i2 = atok[e], i3 = actok[e];
    int i4 = tgap[e]; i4 = i4 < 0 ? 0 : (i4 > TGB_ ? TGB_ : i4);
    int i5 = gid[e];
    float v0 = ttab[(size_t)i0 * H_ + t];
    float v1 = ttab[(size_t)i1 * H_ + t];
    float v2 = ttab[(size_t)i2 * H_ + t];
    float v3 = ttab[(size_t)i3 * H_ + t];
    float v4 = titab[(size_t)i4 * H_ + t];
    float v5 = gtab[(size_t)i5 * H_ + t];
    float s  = v0 + v1 + v2 + v3 + v4 + v5;
    float sq = v0*v0 + v1*v1 + v2*v2 + v3*v3 + v4*v4 + v5*v5;
    #pragma unroll
    for (int off = 32; off > 0; off >>= 1) {
        s  += __shfl_down(s,  off);
        sq += __shfl_down(sq, off);
    }
    __shared__ float red[8];
    int lane = t & 63, w = t >> 6;
    if (lane == 0) { red[w] = s; red[4 + w] = sq; }
    __syncthreads();
    float stot  = red[0] + red[1] + red[2] + red[3];
    float sqtot = red[4] + red[5] + red[6] + red[7];
    float mean = stot * (1.0f / 1536.0f);
    float var  = sqtot * (1.0f / 1536.0f) - mean * mean;
    float rstd = rsqrtf(var + 1e-5f);
    float vv[6] = { v0, v1, v2, v3, v4, v5 };
    unsigned short* orow = xln + (size_t)e * SIXH;
    #pragma unroll
    for (int k = 0; k < 6; ++k) {
        int idx = k * H_ + t;
        float y = (vv[k] - mean) * rstd * gamma[idx] + beta[idx];
        orow[idx] = f2bf(y);
    }
}

// ---------------------------------------------------------------------------
// K2: 8-phase 256x256 bf16 MFMA GEMM (r6 structure, unchanged schedule).
// EPI 0: silu -> bf16 C.   EPI 2: fused scatter epilogue -- write f32 rows
// directly into out[(b,pos)] with bias + pos_table added (posmap >= 0).
// ---------------------------------------------------------------------------
template<int N, int K, int NTN, int EPI>
__global__ __launch_bounds__(512, 2) void gemm256_kernel(
    const unsigned short* __restrict__ A,
    const unsigned short* __restrict__ Bt,
    const float* __restrict__ bias,
    unsigned short* __restrict__ C,
    const int* __restrict__ posmap,
    const float* __restrict__ ptab,
    float* __restrict__ outF)
{
    constexpr int NT = K / 64;        // K-tiles
    constexpr int IT = NT / 2;        // 2 K-tiles per iteration
    constexpr int NBLK = 256 * NTN;   // (M/256) * NTN
    constexpr int CHUNK = NBLK / 8;
    extern __shared__ __align__(16) unsigned short lds[];   // 65536 shorts

    const int bid = blockIdx.x;
    const int wid = (bid & 7) * CHUNK + (bid >> 3);   // XCD-bijective swizzle
    const int mt  = wid / NTN;
    const int m0  = mt * 256;
    const int n0  = (wid - mt * NTN) * 256;

    const int t = threadIdx.x;
    const int w = t >> 6, l = t & 63;
    const int wm = w >> 2, wn = w & 3;
    const int r16 = l & 15, ql = l >> 4;

    // staging sources (pre-swizzled chunk group), advanced +128 shorts/iter
    const int sg = (t & 3) ^ ((t >> 3) & 3);
    const unsigned short* As0 = A  + (size_t)(m0 + (t >> 2)) * K + sg * 8;
    const unsigned short* As1 = As0 + (size_t)128 * K;
    const unsigned short* Bs0 = Bt + (size_t)(n0 + (t >> 2)) * K + sg * 8;
    const unsigned short* Bs1 = Bs0 + (size_t)128 * K;
    unsigned short* ldsb = lds + w * 512;              // wave-uniform dest base

    // fragment read bases (shorts)
    const int fr = (ql ^ ((r16 >> 1) & 3)) * 8;
    const unsigned short* la0 = lds + (wm * 128 + r16) * 32 + fr;          // buf0 A
    const unsigned short* la1 = la0 + 32768;                                // buf1 A
    const unsigned short* lb0 = lds + 16384 + (wn * 64 + r16) * 32 + fr;   // buf0 B
    const unsigned short* lb1 = lb0 + 32768;                                // buf1 B

    f32x4 acc[8][4];
    #pragma unroll
    for (int i = 0; i < 8; ++i)
        #pragma unroll
        for (int j = 0; j < 4; ++j) acc[i][j] = (f32x4)0.0f;

    // stage one unit (2 gloads): dofs/gofs compile-time at all call sites
    auto ST2 = [&](const unsigned short* s0, const unsigned short* s1,
                   int dofs, int gofs) {
        gload_lds16(s0 + gofs, ldsb + dofs);
        gload_lds16(s1 + gofs, ldsb + dofs + 4096);
    };

    // prologue: units 0..5 (kt0 full, kt1 kh0)
    ST2(As0, As1, 0,     0);    // u0 buf0 A kh0
    ST2(Bs0, Bs1, 16384, 0);    // u1 buf0 B kh0
    ST2(As0, As1, 8192,  32);   // u2 buf0 A kh1
    ST2(Bs0, Bs1, 24576, 32);   // u3 buf0 B kh1
    ST2(As0, As1, 32768, 64);   // u4 buf1 A kh0
    ST2(Bs0, Bs1, 49152, 64);   // u5 buf1 B kh0
    asm volatile("s_waitcnt vmcnt(4)\ns_barrier" ::: "memory");

    bf16x8 bq[4];

    auto phase = [&](auto pc, bool last) {
        constexpr int P   = decltype(pc)::v;
        constexpr int BUF = P >> 2;
        constexpr int KK  = (P & 3) >> 1;
        constexpr int MH  = P & 1;
        const unsigned short* ab = (BUF ? la1 : la0) + KK * 8192 + MH * 2048;
        bf16x8 aq[4];
        if constexpr (MH == 0) {
            const unsigned short* bb = (BUF ? lb1 : lb0) + KK * 8192;
            bq[0] = *(const bf16x8*)(bb);
            bq[1] = *(const bf16x8*)(bb + 512);
            bq[2] = *(const bf16x8*)(bb + 1024);
            bq[3] = *(const bf16x8*)(bb + 1536);
        }
        aq[0] = *(const bf16x8*)(ab);
        aq[1] = *(const bf16x8*)(ab + 512);
        aq[2] = *(const bf16x8*)(ab + 1024);
        aq[3] = *(const bf16x8*)(ab + 1536);
        // staging: unit u = 8it+6+P
        if constexpr (P == 0)      {            ST2(As0, As1, 40960, 96);  }
        else if constexpr (P == 1) {            ST2(Bs0, Bs1, 57344, 96);  }
        else if constexpr (P == 2) { if (!last) ST2(As0, As1, 0,     128); }
        else if constexpr (P == 3) { if (!last) ST2(Bs0, Bs1, 16384, 128); }
        else if constexpr (P == 4) { if (!last) ST2(As0, As1, 8192,  160); }
        else if constexpr (P == 5) { if (!last) ST2(Bs0, Bs1, 24576, 160); }
        else if constexpr (P == 6) { if (!last) ST2(As0, As1, 32768, 192); }
        else                       { if (!last) ST2(Bs0, Bs1, 49152, 192); }
        asm volatile("s_barrier" ::: "memory");
        __builtin_amdgcn_s_setprio(1);
        #pragma unroll
        for (int mm = 0; mm < 4; ++mm)
            #pragma unroll
            for (int nn = 0; nn < 4; ++nn)
                acc[MH * 4 + mm][nn] = __builtin_amdgcn_mfma_f32_16x16x32_bf16(
                    aq[mm], bq[nn], acc[MH * 4 + mm][nn], 0, 0, 0);
        __builtin_amdgcn_s_setprio(0);
        if constexpr (P == 3) {
            if (last) asm volatile("s_waitcnt vmcnt(0)\ns_barrier" ::: "memory");
            else      asm volatile("s_waitcnt vmcnt(4)\ns_barrier" ::: "memory");
        } else if constexpr (P == 7) {
            if (!last) asm volatile("s_waitcnt vmcnt(4)\ns_barrier" ::: "memory");
        } else {
            asm volatile("s_barrier" ::: "memory");
        }
    };

    for (int it = 0; it < IT; ++it) {
        const bool last = (it == IT - 1);
        phase(IC<0>{}, last);
        phase(IC<1>{}, last);
        phase(IC<2>{}, last);
        phase(IC<3>{}, last);
        phase(IC<4>{}, last);
        phase(IC<5>{}, last);
        phase(IC<6>{}, last);
        phase(IC<7>{}, last);
        As0 += 128; As1 += 128; Bs0 += 128; Bs1 += 128;
    }

    // epilogue
    if constexpr (EPI == 0) {
        #pragma unroll
        for (int mi = 0; mi < 8; ++mi) {
            #pragma unroll
            for (int ni = 0; ni < 4; ++ni) {
                int col = n0 + wn * 64 + ni * 16 + r16;
                float bv = bias[col];
                #pragma unroll
                for (int j = 0; j < 4; ++j) {
                    int row = m0 + wm * 128 + mi * 16 + ql * 4 + j;
                    float v = acc[mi][ni][j] + bv;
                    v = v / (1.0f + __expf(-v));   // silu
                    C[(size_t)row * N + col] = f2bf(v);
                }
            }
        }
    } else {
        // fused scatter: row -> (b = row>>9, pos = posmap[row]); write f32
        // out[(b,pos)][col] = acc + bias[col] + pos_table[pos][col]
        #pragma unroll
        for (int mi = 0; mi < 8; ++mi) {
            #pragma unroll
            for (int j = 0; j < 4; ++j) {
                int row = m0 + wm * 128 + mi * 16 + ql * 4 + j;
                int pos = posmap[row];
                if (pos >= 0) {
                    float* orow = outF + ((size_t)(row >> 9) * S_ + pos) * H_;
                    const float* prow = ptab + (size_t)pos * H_;
                    #pragma unroll
                    for (int ni = 0; ni < 4; ++ni) {
                        int col = n0 + wn * 64 + ni * 16 + r16;
                        orow[col] = acc[mi][ni][j] + bias[col] + prow[col];
                    }
                }
            }
        }
    }
}

// ---------------------------------------------------------------------------
// K3: per-batch boundary + exclusive cumsum + inverse & forward maps
// idx_map[b][s]: >=0 event, -2 sep, -1 empty.  posmap[b][i]: slot or -1.
// ---------------------------------------------------------------------------
__global__ __launch_bounds__(512) void scan_scatter_kernel(
    const int* __restrict__ gid, const int* __restrict__ lengths,
    int* __restrict__ idx_map, int* __restrict__ shiftb,
    int* __restrict__ posmap)
{
    int b = blockIdx.x, i = threadIdx.x;
    int len = lengths[b];
    int g  = gid[b * L_ + i];
    int gn = (i < L_ - 1) ? gid[b * L_ + i + 1] : g;
    int bnd = (i < len - 1 && g != gn) ? 1 : 0;
    __shared__ int sc[512];
    sc[i] = bnd;
    __syncthreads();
    for (int off = 1; off < 512; off <<= 1) {
        int v = (i >= off) ? sc[i - off] : 0;
        __syncthreads();
        sc[i] += v;
        __syncthreads();
    }
    int incl  = sc[i];
    int total = sc[511];
    int ex = incl - bnd;
    int M = len + total;
    int shift = S_ - M;          // always >= 0
    for (int s = i; s < S_; s += 512) idx_map[b * S_ + s] = -1;
    __syncthreads();
    int p = shift + i + ex;
    if (i < len) {
        idx_map[b * S_ + p] = i;
        if (bnd) idx_map[b * S_ + p + 1] = -2;
        posmap[b * L_ + i] = p;
    } else {
        posmap[b * L_ + i] = -1;
    }
    if (i == 0) shiftb[b] = shift;
}

// ---------------------------------------------------------------------------
// K4: fill non-event slots: zeros (s<shift), sep slots, and the mask plane.
// Event slots are written by GEMM2's fused epilogue (disjoint coverage).
// Block covers 4 s-slots; thread t -> s = s0 + (t>>6), 4 floats at (t&63)*4.
// ---------------------------------------------------------------------------
__global__ __launch_bounds__(256) void fill_kernel(
    const int* __restrict__ idx_map, const int* __restrict__ shiftb,
    const float* __restrict__ ptab, const float* __restrict__ sep,
    float* __restrict__ out)
{
    int b = blockIdx.y;
    int s = blockIdx.x * 4 + (threadIdx.x >> 6);
    if (s >= S_) return;
    int h = (threadIdx.x & 63) * 4;
    int shift = shiftb[b];
    float* orow = out + ((size_t)b * S_ + s) * H_;
    if (s < shift) {
        *(f32x4*)(orow + h) = (f32x4)0.0f;
    } else {
        int idx = idx_map[b * S_ + s];
        if (idx == -2) {
            f32x4 pv = *(const f32x4*)(ptab + (size_t)s * H_ + h);
            f32x4 sv = *(const f32x4*)(sep + h);
            *(f32x4*)(orow + h) = pv + sv;
        }
    }
    if ((threadIdx.x & 63) == 0)
        out[(size_t)B_ * S_ * H_ + (size_t)b * S_ + s] = (s >= shift) ? 1.0f : 0.0f;
}

// ---------------------------------------------------------------------------
extern "C" void kernel_launch(void* const* d_in, const int* in_sizes, int n_in,
                              void* d_out, int out_size, void* d_ws, size_t ws_size,
                              hipStream_t stream)
{
    const int*   tok   = (const int*)d_in[0];
    const int*   ptok  = (const int*)d_in[1];
    const int*   atok  = (const int*)d_in[2];
    const int*   actok = (const int*)d_in[3];
    const int*   tgap  = (const int*)d_in[4];
    const int*   gid   = (const int*)d_in[5];
    const int*   lens  = (const int*)d_in[6];
    const float* ttab  = (const float*)d_in[7];
    const float* titab = (const float*)d_in[8];
    const float* gtab  = (const float*)d_in[9];
    const float* post  = (const float*)d_in[10];
    const float* sep   = (const float*)d_in[11];
    const float* gamma = (const float*)d_in[12];
    const float* beta  = (const float*)d_in[13];
    const float* W1    = (const float*)d_in[14];
    const float* b1    = (const float*)d_in[15];
    const float* W2    = (const float*)d_in[16];
    const float* b2    = (const float*)d_in[17];

    unsigned short* xln  = (unsigned short*)d_ws;                 // BL*1536 bf16
    unsigned short* hbuf = xln  + (size_t)BL_ * SIXH;             // BL*1024 bf16
    unsigned short* W1T  = hbuf + (size_t)BL_ * FOURH;            // 1024*1536 bf16
    unsigned short* W2T  = W1T  + (size_t)FOURH * SIXH;           // 256*1024 bf16
    int* idx_map = (int*)(W2T + (size_t)H_ * FOURH);              // B*S int
    int* shiftb  = idx_map + B_ * S_;                             // B int
    int* posmap  = shiftb + B_;                                   // B*L int
    float* out   = (float*)d_out;

    constexpr int LDS_BYTES = 2 * 32768 * 2;                      // 131072
    (void)hipFuncSetAttribute((const void*)&gemm256_kernel<FOURH, SIXH, 4, 0>,
                              hipFuncAttributeMaxDynamicSharedMemorySize, LDS_BYTES);
    (void)hipFuncSetAttribute((const void*)&gemm256_kernel<H_, FOURH, 1, 2>,
                              hipFuncAttributeMaxDynamicSharedMemorySize, LDS_BYTES);

    // weight transposes (f32 -> bf16, NxK layout for MFMA B-operand)
    transpose_bf16_kernel<<<dim3(SIXH / 32, FOURH / 32), 256, 0, stream>>>(W1, W1T, SIXH, FOURH);
    transpose_bf16_kernel<<<dim3(FOURH / 32, H_ / 32),   256, 0, stream>>>(W2, W2T, FOURH, H_);

    // embed + layernorm
    embed_ln_kernel<<<BL_, 256, 0, stream>>>(tok, ptok, atok, actok, tgap, gid,
                                             ttab, titab, gtab, gamma, beta, xln);

    // scan + maps (needed by GEMM2's fused epilogue)
    scan_scatter_kernel<<<B_, 512, 0, stream>>>(gid, lens, idx_map, shiftb, posmap);

    // MLP: GEMM1 (silu -> hbuf bf16), GEMM2 (fused scatter -> out f32)
    gemm256_kernel<FOURH, SIXH, 4, 0><<<(BL_ / 256) * 4, 512, LDS_BYTES, stream>>>(
        xln, W1T, b1, hbuf, nullptr, nullptr, nullptr);
    gemm256_kernel<H_, FOURH, 1, 2><<<(BL_ / 256) * 1, 512, LDS_BYTES, stream>>>(
        hbuf, W2T, b2, nullptr, posmap, post, out);

    // fill zeros / sep slots / mask plane
    fill_kernel<<<dim3((S_ + 3) / 4, B_), 256, 0, stream>>>(idx_map, shiftb, post, sep, out);
}

// Round 8
// 289.949 us; speedup vs baseline: 1.6243x; 1.5418x over previous
//
#include <hip/hip_runtime.h>

#define B_    128
#define L_    512
#define H_    256
#define TGB_  128
#define S_    1023
#define BL_   (B_ * L_)     // 65536
#define SIXH  1536
#define FOURH 1024

typedef __bf16 bf16_t;
typedef bf16_t bf16x8 __attribute__((ext_vector_type(8)));
typedef float  f32x4  __attribute__((ext_vector_type(4)));
typedef unsigned short u16x4 __attribute__((ext_vector_type(4)));

template<int P> struct IC { static constexpr int v = P; };

__device__ __forceinline__ unsigned short f2bf(float f) {
    union { float f; unsigned u; } v; v.f = f;
    unsigned u = v.u;
    unsigned r = u + 0x7FFFu + ((u >> 16) & 1u);   // round-to-nearest-even
    return (unsigned short)(r >> 16);
}

__device__ __forceinline__ void gload_lds16(const void* g, void* l) {
    __builtin_amdgcn_global_load_lds(
        (__attribute__((address_space(1))) void*)(void*)(g),
        (__attribute__((address_space(3))) void*)(l), 16, 0, 0);
}

// ---------------------------------------------------------------------------
// K0: transpose + f32->bf16 convert:  in (R x C) f32  ->  out (C x R) bf16
// ---------------------------------------------------------------------------
__global__ __launch_bounds__(256) void transpose_bf16_kernel(
    const float* __restrict__ in, unsigned short* __restrict__ out,
    int R, int C)
{
    __shared__ float tile[32][33];
    int rb = blockIdx.x * 32, cb = blockIdx.y * 32;
    int tx = threadIdx.x & 31, ty = threadIdx.x >> 5;   // 32 x 8
    #pragma unroll
    for (int d = 0; d < 32; d += 8)
        tile[ty + d][tx] = in[(size_t)(rb + ty + d) * C + cb + tx];
    __syncthreads();
    #pragma unroll
    for (int d = 0; d < 32; d += 8)
        out[(size_t)(cb + ty + d) * R + rb + tx] = f2bf(tile[tx][ty + d]);
}

// ---------------------------------------------------------------------------
// Kp: prefix of lengths -> prefix[b], V (device), pad outslot[V..V+256)=-1
// ---------------------------------------------------------------------------
__global__ __launch_bounds__(128) void prefix_kernel(
    const int* __restrict__ lens, int* __restrict__ prefix,
    int* __restrict__ Vdev, int* __restrict__ outslot)
{
    __shared__ int sV;
    if (threadIdx.x == 0) {
        int acc = 0;
        for (int b = 0; b < B_; ++b) { prefix[b] = acc; acc += lens[b]; }
        *Vdev = acc; sV = acc;
    }
    __syncthreads();
    int V = sV;
    outslot[V + threadIdx.x] = -1;
    outslot[V + 128 + threadIdx.x] = -1;
}

// ---------------------------------------------------------------------------
// K1: compacted gather + LayerNorm. One wave (64 lanes) per valid event j.
// f32x4 gathers (16 B/lane), shfl-only reduction, ushort4 bf16 writes.
// ---------------------------------------------------------------------------
__global__ __launch_bounds__(256) void embed_ln_kernel(
    const int* __restrict__ tok,  const int* __restrict__ ptok,
    const int* __restrict__ atok, const int* __restrict__ actok,
    const int* __restrict__ tgap, const int* __restrict__ gid,
    const float* __restrict__ ttab, const float* __restrict__ titab,
    const float* __restrict__ gtab, const float* __restrict__ gamma,
    const float* __restrict__ beta, const int* __restrict__ row_id,
    const int* __restrict__ Vdev, unsigned short* __restrict__ xln)
{
    int j = blockIdx.x * 4 + (threadIdx.x >> 6);
    if (j >= *Vdev) return;
    int l = threadIdx.x & 63;
    int rid = row_id[j];
    int i0 = tok[rid], i1 = ptok[rid], i2 = atok[rid], i3 = actok[rid];
    int i4 = tgap[rid]; i4 = i4 < 0 ? 0 : (i4 > TGB_ ? TGB_ : i4);
    int i5 = gid[rid];
    f32x4 v[6];
    v[0] = *(const f32x4*)(ttab  + (size_t)i0 * H_ + l * 4);
    v[1] = *(const f32x4*)(ttab  + (size_t)i1 * H_ + l * 4);
    v[2] = *(const f32x4*)(ttab  + (size_t)i2 * H_ + l * 4);
    v[3] = *(const f32x4*)(ttab  + (size_t)i3 * H_ + l * 4);
    v[4] = *(const f32x4*)(titab + (size_t)i4 * H_ + l * 4);
    v[5] = *(const f32x4*)(gtab  + (size_t)i5 * H_ + l * 4);
    float s = 0.0f, sq = 0.0f;
    #pragma unroll
    for (int k = 0; k < 6; ++k)
        #pragma unroll
        for (int c = 0; c < 4; ++c) { float f = v[k][c]; s += f; sq += f * f; }
    #pragma unroll
    for (int off = 32; off > 0; off >>= 1) {
        s  += __shfl_xor(s,  off);
        sq += __shfl_xor(sq, off);
    }
    float mean = s * (1.0f / 1536.0f);
    float var  = sq * (1.0f / 1536.0f) - mean * mean;
    float rstd = rsqrtf(var + 1e-5f);
    unsigned short* orow = xln + (size_t)j * SIXH;
    #pragma unroll
    for (int k = 0; k < 6; ++k) {
        f32x4 g = *(const f32x4*)(gamma + k * H_ + l * 4);
        f32x4 b = *(const f32x4*)(beta  + k * H_ + l * 4);
        u16x4 o;
        #pragma unroll
        for (int c = 0; c < 4; ++c)
            o[c] = f2bf((v[k][c] - mean) * rstd * g[c] + b[c]);
        *(u16x4*)(orow + k * H_ + l * 4) = o;
    }
}

// ---------------------------------------------------------------------------
// K2: 8-phase 256x256 bf16 MFMA GEMM (r6 schedule, unchanged) over the
// compacted M = V rows. Blocks beyond nact = ceil(V/256)*NTN exit; m204
// bijective dynamic XCD swizzle over nact keeps per-XCD balance.
// EPI 0: silu -> bf16 C.   EPI 2: fused scatter epilogue via outslot/posC.
// ---------------------------------------------------------------------------
template<int N, int K, int NTN, int EPI>
__global__ __launch_bounds__(512, 2) void gemm256_kernel(
    const unsigned short* __restrict__ A,
    const unsigned short* __restrict__ Bt,
    const float* __restrict__ bias,
    unsigned short* __restrict__ C,
    const int* __restrict__ outslot,
    const int* __restrict__ posC,
    const float* __restrict__ ptab,
    float* __restrict__ outF,
    const int* __restrict__ Vdev)
{
    constexpr int NT = K / 64;        // K-tiles
    constexpr int IT = NT / 2;        // 2 K-tiles per iteration
    extern __shared__ __align__(16) unsigned short lds[];   // 65536 shorts

    const int V = *Vdev;
    const int nact = ((V + 255) >> 8) * NTN;
    const int bid = blockIdx.x;
    if (bid >= nact) return;
    // m204 bijective XCD swizzle over nact blocks
    const int q = nact >> 3, r = nact & 7, x = bid & 7, o = bid >> 3;
    const int wid = (x < r ? x * (q + 1) : r * (q + 1) + (x - r) * q) + o;
    const int mt  = wid / NTN;
    const int m0  = mt * 256;
    const int n0  = (wid - mt * NTN) * 256;

    const int t = threadIdx.x;
    const int w = t >> 6, l = t & 63;
    const int wm = w >> 2, wn = w & 3;
    const int r16 = l & 15, ql = l >> 4;

    // staging sources (pre-swizzled chunk group), advanced +128 shorts/iter
    const int sg = (t & 3) ^ ((t >> 3) & 3);
    const unsigned short* As0 = A  + (size_t)(m0 + (t >> 2)) * K + sg * 8;
    const unsigned short* As1 = As0 + (size_t)128 * K;
    const unsigned short* Bs0 = Bt + (size_t)(n0 + (t >> 2)) * K + sg * 8;
    const unsigned short* Bs1 = Bs0 + (size_t)128 * K;
    unsigned short* ldsb = lds + w * 512;              // wave-uniform dest base

    // fragment read bases (shorts)
    const int fr = (ql ^ ((r16 >> 1) & 3)) * 8;
    const unsigned short* la0 = lds + (wm * 128 + r16) * 32 + fr;          // buf0 A
    const unsigned short* la1 = la0 + 32768;                                // buf1 A
    const unsigned short* lb0 = lds + 16384 + (wn * 64 + r16) * 32 + fr;   // buf0 B
    const unsigned short* lb1 = lb0 + 32768;                                // buf1 B

    f32x4 acc[8][4];
    #pragma unroll
    for (int i = 0; i < 8; ++i)
        #pragma unroll
        for (int j = 0; j < 4; ++j) acc[i][j] = (f32x4)0.0f;

    auto ST2 = [&](const unsigned short* s0, const unsigned short* s1,
                   int dofs, int gofs) {
        gload_lds16(s0 + gofs, ldsb + dofs);
        gload_lds16(s1 + gofs, ldsb + dofs + 4096);
    };

    // prologue: units 0..5 (kt0 full, kt1 kh0)
    ST2(As0, As1, 0,     0);
    ST2(Bs0, Bs1, 16384, 0);
    ST2(As0, As1, 8192,  32);
    ST2(Bs0, Bs1, 24576, 32);
    ST2(As0, As1, 32768, 64);
    ST2(Bs0, Bs1, 49152, 64);
    asm volatile("s_waitcnt vmcnt(4)\ns_barrier" ::: "memory");

    bf16x8 bq[4];

    auto phase = [&](auto pc, bool last) {
        constexpr int P   = decltype(pc)::v;
        constexpr int BUF = P >> 2;
        constexpr int KK  = (P & 3) >> 1;
        constexpr int MH  = P & 1;
        const unsigned short* ab = (BUF ? la1 : la0) + KK * 8192 + MH * 2048;
        bf16x8 aq[4];
        if constexpr (MH == 0) {
            const unsigned short* bb = (BUF ? lb1 : lb0) + KK * 8192;
            bq[0] = *(const bf16x8*)(bb);
            bq[1] = *(const bf16x8*)(bb + 512);
            bq[2] = *(const bf16x8*)(bb + 1024);
            bq[3] = *(const bf16x8*)(bb + 1536);
        }
        aq[0] = *(const bf16x8*)(ab);
        aq[1] = *(const bf16x8*)(ab + 512);
        aq[2] = *(const bf16x8*)(ab + 1024);
        aq[3] = *(const bf16x8*)(ab + 1536);
        // staging: unit u = 8it+6+P
        if constexpr (P == 0)      {            ST2(As0, As1, 40960, 96);  }
        else if constexpr (P == 1) {            ST2(Bs0, Bs1, 57344, 96);  }
        else if constexpr (P == 2) { if (!last) ST2(As0, As1, 0,     128); }
        else if constexpr (P == 3) { if (!last) ST2(Bs0, Bs1, 16384, 128); }
        else if constexpr (P == 4) { if (!last) ST2(As0, As1, 8192,  160); }
        else if constexpr (P == 5) { if (!last) ST2(Bs0, Bs1, 24576, 160); }
        else if constexpr (P == 6) { if (!last) ST2(As0, As1, 32768, 192); }
        else                       { if (!last) ST2(Bs0, Bs1, 49152, 192); }
        asm volatile("s_barrier" ::: "memory");
        __builtin_amdgcn_s_setprio(1);
        #pragma unroll
        for (int mm = 0; mm < 4; ++mm)
            #pragma unroll
            for (int nn = 0; nn < 4; ++nn)
                acc[MH * 4 + mm][nn] = __builtin_amdgcn_mfma_f32_16x16x32_bf16(
                    aq[mm], bq[nn], acc[MH * 4 + mm][nn], 0, 0, 0);
        __builtin_amdgcn_s_setprio(0);
        if constexpr (P == 3) {
            if (last) asm volatile("s_waitcnt vmcnt(0)\ns_barrier" ::: "memory");
            else      asm volatile("s_waitcnt vmcnt(4)\ns_barrier" ::: "memory");
        } else if constexpr (P == 7) {
            if (!last) asm volatile("s_waitcnt vmcnt(4)\ns_barrier" ::: "memory");
        } else {
            asm volatile("s_barrier" ::: "memory");
        }
    };

    for (int it = 0; it < IT; ++it) {
        const bool last = (it == IT - 1);
        phase(IC<0>{}, last);
        phase(IC<1>{}, last);
        phase(IC<2>{}, last);
        phase(IC<3>{}, last);
        phase(IC<4>{}, last);
        phase(IC<5>{}, last);
        phase(IC<6>{}, last);
        phase(IC<7>{}, last);
        As0 += 128; As1 += 128; Bs0 += 128; Bs1 += 128;
    }

    // epilogue
    if constexpr (EPI == 0) {
        #pragma unroll
        for (int mi = 0; mi < 8; ++mi) {
            #pragma unroll
            for (int ni = 0; ni < 4; ++ni) {
                int col = n0 + wn * 64 + ni * 16 + r16;
                float bv = bias[col];
                #pragma unroll
                for (int j = 0; j < 4; ++j) {
                    int row = m0 + wm * 128 + mi * 16 + ql * 4 + j;
                    float v = acc[mi][ni][j] + bv;
                    v = v / (1.0f + __expf(-v));   // silu
                    C[(size_t)row * N + col] = f2bf(v);
                }
            }
        }
    } else {
        // fused scatter: compact row j -> out slot (b*S+pos), + bias + pos_table
        #pragma unroll
        for (int mi = 0; mi < 8; ++mi) {
            #pragma unroll
            for (int j = 0; j < 4; ++j) {
                int row = m0 + wm * 128 + mi * 16 + ql * 4 + j;
                int slot = outslot[row];
                if (slot >= 0) {
                    float* orow = outF + (size_t)slot * H_;
                    const float* prow = ptab + (size_t)posC[row] * H_;
                    #pragma unroll
                    for (int ni = 0; ni < 4; ++ni) {
                        int col = n0 + wn * 64 + ni * 16 + r16;
                        orow[col] = acc[mi][ni][j] + bias[col] + prow[col];
                    }
                }
            }
        }
    }
}

// ---------------------------------------------------------------------------
// K3: per-batch boundary + cumsum + inverse map + compact forward maps
// ---------------------------------------------------------------------------
__global__ __launch_bounds__(512) void scan_scatter_kernel(
    const int* __restrict__ gid, const int* __restrict__ lengths,
    const int* __restrict__ prefix,
    int* __restrict__ idx_map, int* __restrict__ shiftb,
    int* __restrict__ row_id, int* __restrict__ outslot,
    int* __restrict__ posC)
{
    int b = blockIdx.x, i = threadIdx.x;
    int len = lengths[b];
    int g  = gid[b * L_ + i];
    int gn = (i < L_ - 1) ? gid[b * L_ + i + 1] : g;
    int bnd = (i < len - 1 && g != gn) ? 1 : 0;
    __shared__ int sc[512];
    sc[i] = bnd;
    __syncthreads();
    for (int off = 1; off < 512; off <<= 1) {
        int v = (i >= off) ? sc[i - off] : 0;
        __syncthreads();
        sc[i] += v;
        __syncthreads();
    }
    int incl  = sc[i];
    int total = sc[511];
    int ex = incl - bnd;
    int M = len + total;
    int shift = S_ - M;          // always >= 0
    for (int s = i; s < S_; s += 512) idx_map[b * S_ + s] = -1;
    __syncthreads();
    if (i < len) {
        int p = shift + i + ex;
        idx_map[b * S_ + p] = i;
        if (bnd) idx_map[b * S_ + p + 1] = -2;
        int j = prefix[b] + i;
        row_id[j]  = b * L_ + i;
        outslot[j] = b * S_ + p;
        posC[j]    = p;
    }
    if (i == 0) shiftb[b] = shift;
}

// ---------------------------------------------------------------------------
// K4: fill non-event slots: zeros (s<shift), sep slots, and the mask plane.
// ---------------------------------------------------------------------------
__global__ __launch_bounds__(256) void fill_kernel(
    const int* __restrict__ idx_map, const int* __restrict__ shiftb,
    const float* __restrict__ ptab, const float* __restrict__ sep,
    float* __restrict__ out)
{
    int b = blockIdx.y;
    int s = blockIdx.x * 4 + (threadIdx.x >> 6);
    if (s >= S_) return;
    int h = (threadIdx.x & 63) * 4;
    int shift = shiftb[b];
    float* orow = out + ((size_t)b * S_ + s) * H_;
    if (s < shift) {
        *(f32x4*)(orow + h) = (f32x4)0.0f;
    } else {
        int idx = idx_map[b * S_ + s];
        if (idx == -2) {
            f32x4 pv = *(const f32x4*)(ptab + (size_t)s * H_ + h);
            f32x4 sv = *(const f32x4*)(sep + h);
            *(f32x4*)(orow + h) = pv + sv;
        }
    }
    if ((threadIdx.x & 63) == 0)
        out[(size_t)B_ * S_ * H_ + (size_t)b * S_ + s] = (s >= shift) ? 1.0f : 0.0f;
}

// ---------------------------------------------------------------------------
extern "C" void kernel_launch(void* const* d_in, const int* in_sizes, int n_in,
                              void* d_out, int out_size, void* d_ws, size_t ws_size,
                              hipStream_t stream)
{
    const int*   tok   = (const int*)d_in[0];
    const int*   ptok  = (const int*)d_in[1];
    const int*   atok  = (const int*)d_in[2];
    const int*   actok = (const int*)d_in[3];
    const int*   tgap  = (const int*)d_in[4];
    const int*   gid   = (const int*)d_in[5];
    const int*   lens  = (const int*)d_in[6];
    const float* ttab  = (const float*)d_in[7];
    const float* titab = (const float*)d_in[8];
    const float* gtab  = (const float*)d_in[9];
    const float* post  = (const float*)d_in[10];
    const float* sep   = (const float*)d_in[11];
    const float* gamma = (const float*)d_in[12];
    const float* beta  = (const float*)d_in[13];
    const float* W1    = (const float*)d_in[14];
    const float* b1    = (const float*)d_in[15];
    const float* W2    = (const float*)d_in[16];
    const float* b2    = (const float*)d_in[17];

    unsigned short* xln  = (unsigned short*)d_ws;                 // BL*1536 bf16
    unsigned short* hbuf = xln  + (size_t)BL_ * SIXH;             // BL*1024 bf16
    unsigned short* W1T  = hbuf + (size_t)BL_ * FOURH;            // 1024*1536 bf16
    unsigned short* W2T  = W1T  + (size_t)FOURH * SIXH;           // 256*1024 bf16
    int* idx_map = (int*)(W2T + (size_t)H_ * FOURH);              // B*S int
    int* shiftb  = idx_map + B_ * S_;                             // B
    int* prefix  = shiftb + B_;                                   // B
    int* Vdev    = prefix + B_;                                   // 1 (+pad)
    int* row_id  = Vdev + 4;                                      // BL
    int* outslot = row_id + BL_;                                  // BL+256
    int* posC    = outslot + BL_ + 256;                           // BL+256
    float* out   = (float*)d_out;

    constexpr int LDS_BYTES = 2 * 32768 * 2;                      // 131072
    (void)hipFuncSetAttribute((const void*)&gemm256_kernel<FOURH, SIXH, 4, 0>,
                              hipFuncAttributeMaxDynamicSharedMemorySize, LDS_BYTES);
    (void)hipFuncSetAttribute((const void*)&gemm256_kernel<H_, FOURH, 1, 2>,
                              hipFuncAttributeMaxDynamicSharedMemorySize, LDS_BYTES);

    // weight transposes (independent)
    transpose_bf16_kernel<<<dim3(SIXH / 32, FOURH / 32), 256, 0, stream>>>(W1, W1T, SIXH, FOURH);
    transpose_bf16_kernel<<<dim3(FOURH / 32, H_ / 32),   256, 0, stream>>>(W2, W2T, FOURH, H_);

    // prefix + V (+ outslot pad), then scan + compact maps
    prefix_kernel<<<1, 128, 0, stream>>>(lens, prefix, Vdev, outslot);
    scan_scatter_kernel<<<B_, 512, 0, stream>>>(gid, lens, prefix, idx_map, shiftb,
                                                row_id, outslot, posC);

    // compacted embed + layernorm
    embed_ln_kernel<<<BL_ / 4, 256, 0, stream>>>(tok, ptok, atok, actok, tgap, gid,
                                                 ttab, titab, gtab, gamma, beta,
                                                 row_id, Vdev, xln);

    // MLP over compacted rows
    gemm256_kernel<FOURH, SIXH, 4, 0><<<(BL_ / 256) * 4, 512, LDS_BYTES, stream>>>(
        xln, W1T, b1, hbuf, nullptr, nullptr, nullptr, nullptr, Vdev);
    gemm256_kernel<H_, FOURH, 1, 2><<<(BL_ / 256) * 1, 512, LDS_BYTES, stream>>>(
        hbuf, W2T, b2, nullptr, outslot, posC, post, out, Vdev);

    // fill zeros / sep slots / mask plane
    fill_kernel<<<dim3((S_ + 3) / 4, B_), 256, 0, stream>>>(idx_map, shiftb, post, sep, out);
}

// Round 9
// 282.435 us; speedup vs baseline: 1.6675x; 1.0266x over previous
//
#include <hip/hip_runtime.h>

#define B_    128
#define L_    512
#define H_    256
#define TGB_  128
#define S_    1023
#define BL_   (B_ * L_)     // 65536
#define SIXH  1536
#define FOURH 1024

typedef __bf16 bf16_t;
typedef bf16_t bf16x8 __attribute__((ext_vector_type(8)));
typedef float  f32x4  __attribute__((ext_vector_type(4)));
typedef unsigned short u16x4 __attribute__((ext_vector_type(4)));

template<int P> struct IC { static constexpr int v = P; };

__device__ __forceinline__ unsigned short f2bf(float f) {
    union { float f; unsigned u; } v; v.f = f;
    unsigned u = v.u;
    unsigned r = u + 0x7FFFu + ((u >> 16) & 1u);   // round-to-nearest-even
    return (unsigned short)(r >> 16);
}

__device__ __forceinline__ void gload_lds16(const void* g, void* l) {
    __builtin_amdgcn_global_load_lds(
        (__attribute__((address_space(1))) void*)(void*)(g),
        (__attribute__((address_space(3))) void*)(l), 16, 0, 0);
}

// ---------------------------------------------------------------------------
// K0: transpose + f32->bf16 convert:  in (R x C) f32  ->  out (C x R) bf16
// ---------------------------------------------------------------------------
__global__ __launch_bounds__(256) void transpose_bf16_kernel(
    const float* __restrict__ in, unsigned short* __restrict__ out,
    int R, int C)
{
    __shared__ float tile[32][33];
    int rb = blockIdx.x * 32, cb = blockIdx.y * 32;
    int tx = threadIdx.x & 31, ty = threadIdx.x >> 5;   // 32 x 8
    #pragma unroll
    for (int d = 0; d < 32; d += 8)
        tile[ty + d][tx] = in[(size_t)(rb + ty + d) * C + cb + tx];
    __syncthreads();
    #pragma unroll
    for (int d = 0; d < 32; d += 8)
        out[(size_t)(cb + ty + d) * R + rb + tx] = f2bf(tile[tx][ty + d]);
}

// ---------------------------------------------------------------------------
// K1: compacted gather + LayerNorm. One wave per valid event j.
// ---------------------------------------------------------------------------
__global__ __launch_bounds__(256) void embed_ln_kernel(
    const int* __restrict__ tok,  const int* __restrict__ ptok,
    const int* __restrict__ atok, const int* __restrict__ actok,
    const int* __restrict__ tgap, const int* __restrict__ gid,
    const float* __restrict__ ttab, const float* __restrict__ titab,
    const float* __restrict__ gtab, const float* __restrict__ gamma,
    const float* __restrict__ beta, const int* __restrict__ row_id,
    const int* __restrict__ Vdev, unsigned short* __restrict__ xln)
{
    int j = blockIdx.x * 4 + (threadIdx.x >> 6);
    if (j >= *Vdev) return;
    int l = threadIdx.x & 63;
    int rid = row_id[j];
    int i0 = tok[rid], i1 = ptok[rid], i2 = atok[rid], i3 = actok[rid];
    int i4 = tgap[rid]; i4 = i4 < 0 ? 0 : (i4 > TGB_ ? TGB_ : i4);
    int i5 = gid[rid];
    f32x4 v[6];
    v[0] = *(const f32x4*)(ttab  + (size_t)i0 * H_ + l * 4);
    v[1] = *(const f32x4*)(ttab  + (size_t)i1 * H_ + l * 4);
    v[2] = *(const f32x4*)(ttab  + (size_t)i2 * H_ + l * 4);
    v[3] = *(const f32x4*)(ttab  + (size_t)i3 * H_ + l * 4);
    v[4] = *(const f32x4*)(titab + (size_t)i4 * H_ + l * 4);
    v[5] = *(const f32x4*)(gtab  + (size_t)i5 * H_ + l * 4);
    float s = 0.0f, sq = 0.0f;
    #pragma unroll
    for (int k = 0; k < 6; ++k)
        #pragma unroll
        for (int c = 0; c < 4; ++c) { float f = v[k][c]; s += f; sq += f * f; }
    #pragma unroll
    for (int off = 32; off > 0; off >>= 1) {
        s  += __shfl_xor(s,  off);
        sq += __shfl_xor(sq, off);
    }
    float mean = s * (1.0f / 1536.0f);
    float var  = sq * (1.0f / 1536.0f) - mean * mean;
    float rstd = rsqrtf(var + 1e-5f);
    unsigned short* orow = xln + (size_t)j * SIXH;
    #pragma unroll
    for (int k = 0; k < 6; ++k) {
        f32x4 g = *(const f32x4*)(gamma + k * H_ + l * 4);
        f32x4 b = *(const f32x4*)(beta  + k * H_ + l * 4);
        u16x4 o;
        #pragma unroll
        for (int c = 0; c < 4; ++c)
            o[c] = f2bf((v[k][c] - mean) * rstd * g[c] + b[c]);
        *(u16x4*)(orow + k * H_ + l * 4) = o;
    }
}

// ---------------------------------------------------------------------------
// K2: 8-phase 256x256 bf16 MFMA GEMM1 (r6 schedule, persistent grid of 512).
// silu epilogue -> hbuf bf16. M = compacted V rows (blocks loop over tiles).
// ---------------------------------------------------------------------------
__global__ __launch_bounds__(512, 2) void gemm1_kernel(
    const unsigned short* __restrict__ A,
    const unsigned short* __restrict__ Bt,
    const float* __restrict__ bias,
    unsigned short* __restrict__ C,
    const int* __restrict__ Vdev)
{
    constexpr int N = FOURH, K = SIXH, NTN = 4;
    constexpr int NT = K / 64;        // 24 K-tiles
    constexpr int IT = NT / 2;        // 12 iterations
    extern __shared__ __align__(16) unsigned short lds[];

    const int V = *Vdev;
    const int nact = ((V + 255) >> 8) * NTN;
    const int q = nact >> 3, r = nact & 7;

    const int t = threadIdx.x;
    const int w = t >> 6, l = t & 63;
    const int wm = w >> 2, wn = w & 3;
    const int r16 = l & 15, ql = l >> 4;
    const int sg = (t & 3) ^ ((t >> 3) & 3);
    unsigned short* ldsb = lds + w * 512;
    const int fr = (ql ^ ((r16 >> 1) & 3)) * 8;

    for (int bidv = blockIdx.x; bidv < nact; bidv += 512) {
        // m204 bijective XCD swizzle over nact
        const int x = bidv & 7, o = bidv >> 3;
        const int wid = (x < r ? x * (q + 1) : r * (q + 1) + (x - r) * q) + o;
        const int mt  = wid / NTN;
        const int m0  = mt * 256;
        const int n0  = (wid - mt * NTN) * 256;

        const unsigned short* As0 = A  + (size_t)(m0 + (t >> 2)) * K + sg * 8;
        const unsigned short* As1 = As0 + (size_t)128 * K;
        const unsigned short* Bs0 = Bt + (size_t)(n0 + (t >> 2)) * K + sg * 8;
        const unsigned short* Bs1 = Bs0 + (size_t)128 * K;
        const unsigned short* la0 = lds + (wm * 128 + r16) * 32 + fr;
        const unsigned short* la1 = la0 + 32768;
        const unsigned short* lb0 = lds + 16384 + (wn * 64 + r16) * 32 + fr;
        const unsigned short* lb1 = lb0 + 32768;

        f32x4 acc[8][4];
        #pragma unroll
        for (int i = 0; i < 8; ++i)
            #pragma unroll
            for (int j = 0; j < 4; ++j) acc[i][j] = (f32x4)0.0f;

        auto ST2 = [&](const unsigned short* s0, const unsigned short* s1,
                       int dofs, int gofs) {
            gload_lds16(s0 + gofs, ldsb + dofs);
            gload_lds16(s1 + gofs, ldsb + dofs + 4096);
        };

        if (bidv != (int)blockIdx.x) __syncthreads();   // LDS WAR guard across tiles

        // prologue: units 0..5 (kt0 full, kt1 kh0)
        ST2(As0, As1, 0,     0);
        ST2(Bs0, Bs1, 16384, 0);
        ST2(As0, As1, 8192,  32);
        ST2(Bs0, Bs1, 24576, 32);
        ST2(As0, As1, 32768, 64);
        ST2(Bs0, Bs1, 49152, 64);
        asm volatile("s_waitcnt vmcnt(4)\ns_barrier" ::: "memory");

        bf16x8 bq[4];

        auto phase = [&](auto pc, bool last) {
            constexpr int P   = decltype(pc)::v;
            constexpr int BUF = P >> 2;
            constexpr int KK  = (P & 3) >> 1;
            constexpr int MH  = P & 1;
            const unsigned short* ab = (BUF ? la1 : la0) + KK * 8192 + MH * 2048;
            bf16x8 aq[4];
            if constexpr (MH == 0) {
                const unsigned short* bb = (BUF ? lb1 : lb0) + KK * 8192;
                bq[0] = *(const bf16x8*)(bb);
                bq[1] = *(const bf16x8*)(bb + 512);
                bq[2] = *(const bf16x8*)(bb + 1024);
                bq[3] = *(const bf16x8*)(bb + 1536);
            }
            aq[0] = *(const bf16x8*)(ab);
            aq[1] = *(const bf16x8*)(ab + 512);
            aq[2] = *(const bf16x8*)(ab + 1024);
            aq[3] = *(const bf16x8*)(ab + 1536);
            if constexpr (P == 0)      {            ST2(As0, As1, 40960, 96);  }
            else if constexpr (P == 1) {            ST2(Bs0, Bs1, 57344, 96);  }
            else if constexpr (P == 2) { if (!last) ST2(As0, As1, 0,     128); }
            else if constexpr (P == 3) { if (!last) ST2(Bs0, Bs1, 16384, 128); }
            else if constexpr (P == 4) { if (!last) ST2(As0, As1, 8192,  160); }
            else if constexpr (P == 5) { if (!last) ST2(Bs0, Bs1, 24576, 160); }
            else if constexpr (P == 6) { if (!last) ST2(As0, As1, 32768, 192); }
            else                       { if (!last) ST2(Bs0, Bs1, 49152, 192); }
            asm volatile("s_barrier" ::: "memory");
            __builtin_amdgcn_s_setprio(1);
            #pragma unroll
            for (int mm = 0; mm < 4; ++mm)
                #pragma unroll
                for (int nn = 0; nn < 4; ++nn)
                    acc[MH * 4 + mm][nn] = __builtin_amdgcn_mfma_f32_16x16x32_bf16(
                        aq[mm], bq[nn], acc[MH * 4 + mm][nn], 0, 0, 0);
            __builtin_amdgcn_s_setprio(0);
            if constexpr (P == 3) {
                if (last) asm volatile("s_waitcnt vmcnt(0)\ns_barrier" ::: "memory");
                else      asm volatile("s_waitcnt vmcnt(4)\ns_barrier" ::: "memory");
            } else if constexpr (P == 7) {
                if (!last) asm volatile("s_waitcnt vmcnt(4)\ns_barrier" ::: "memory");
            } else {
                asm volatile("s_barrier" ::: "memory");
            }
        };

        for (int it = 0; it < IT; ++it) {
            const bool last = (it == IT - 1);
            phase(IC<0>{}, last);
            phase(IC<1>{}, last);
            phase(IC<2>{}, last);
            phase(IC<3>{}, last);
            phase(IC<4>{}, last);
            phase(IC<5>{}, last);
            phase(IC<6>{}, last);
            phase(IC<7>{}, last);
            As0 += 128; As1 += 128; Bs0 += 128; Bs1 += 128;
        }

        #pragma unroll
        for (int mi = 0; mi < 8; ++mi) {
            #pragma unroll
            for (int ni = 0; ni < 4; ++ni) {
                int col = n0 + wn * 64 + ni * 16 + r16;
                float bv = bias[col];
                #pragma unroll
                for (int j = 0; j < 4; ++j) {
                    int row = m0 + wm * 128 + mi * 16 + ql * 4 + j;
                    float v = acc[mi][ni][j] + bv;
                    v = v / (1.0f + __expf(-v));   // silu
                    C[(size_t)row * N + col] = f2bf(v);
                }
            }
        }
    }
}

// ---------------------------------------------------------------------------
// K2b: GEMM2 = r3-verified ring-3 pipeline, BM=256 x BN=128, K=1024,
// 512 thr = 8 waves (4m x 2n), counted vmcnt(6), 144 KiB LDS.
// NTN=2 n-split -> ~2x blocks vs 256^2 (full CU occupancy after compaction).
// Fused scatter epilogue: out[(slot)][col] = acc + b2[col] + pos_table.
// ---------------------------------------------------------------------------
__global__ __launch_bounds__(512, 2) void gemm2_kernel(
    const unsigned short* __restrict__ A,      // hbuf (V x 1024)
    const unsigned short* __restrict__ Bt,     // W2T (256 x 1024)
    const float* __restrict__ bias,
    const int* __restrict__ outslot,
    const int* __restrict__ posC,
    const float* __restrict__ ptab,
    float* __restrict__ outF,
    const int* __restrict__ Vdev)
{
    constexpr int K = FOURH, NT = K / 64;     // 16 K-tiles
    constexpr int ASLOT = 256 * 64;
    constexpr int BSLOT = 128 * 64;
    extern __shared__ __align__(16) unsigned short lds[];
    unsigned short* sA = lds;
    unsigned short* sB = lds + 3 * ASLOT;

    const int V = *Vdev;
    const int nact = ((V + 255) >> 8) * 2;
    const int bid = blockIdx.x;
    if (bid >= nact) return;
    const int qd = nact >> 3, rd = nact & 7, x = bid & 7, o = bid >> 3;
    const int wid = (x < rd ? x * (qd + 1) : rd * (qd + 1) + (x - rd) * qd) + o;
    const int m0 = (wid >> 1) * 256;
    const int n0 = (wid & 1) * 128;

    int t = threadIdx.x;
    int w = t >> 6, l = t & 63;
    int srow = t >> 3;
    int scg  = (t & 7) ^ (srow & 7);
    const unsigned short* Ag = A  + (size_t)(m0 + srow) * K + scg * 8;
    const unsigned short* Bg = Bt + (size_t)(n0 + srow) * K + scg * 8;
    unsigned short* stA = sA + w * 512;
    unsigned short* stB = sB + w * 512;

    int r16 = l & 15, q = l >> 4;
    int wm = w >> 1, wn = w & 1;             // 4m x 2n
    int xr = r16 & 7;
    const int aoff = (wm * 64 + r16) * 64;
    const int boff = (wn * 64 + r16) * 64;
    const int c0 = ((0 + q) ^ xr) * 8;
    const int c1 = ((4 + q) ^ xr) * 8;

    f32x4 acc[4][4];
    #pragma unroll
    for (int i = 0; i < 4; ++i)
        #pragma unroll
        for (int j = 0; j < 4; ++j) acc[i][j] = (f32x4)0.0f;

    // prologue: kt=0 -> slot0, kt=1 -> slot1
    #pragma unroll
    for (int j = 0; j < 4; ++j) gload_lds16(Ag + (size_t)j * 64 * K, stA + j * 4096);
    #pragma unroll
    for (int j = 0; j < 2; ++j) gload_lds16(Bg + (size_t)j * 64 * K, stB + j * 4096);
    #pragma unroll
    for (int j = 0; j < 4; ++j) gload_lds16(Ag + (size_t)j * 64 * K + 64, stA + ASLOT + j * 4096);
    #pragma unroll
    for (int j = 0; j < 2; ++j) gload_lds16(Bg + (size_t)j * 64 * K + 64, stB + BSLOT + j * 4096);
    asm volatile("s_waitcnt vmcnt(6)\ns_barrier" ::: "memory");

    int s = 0;
    for (int kt = 0; kt < NT; ++kt) {
        const unsigned short* sAs = sA + s * ASLOT;
        const unsigned short* sBs = sB + s * BSLOT;
        int spf = s + 2; if (spf >= 3) spf -= 3;
        const size_t gofs = (size_t)(kt + 2) * 64;
        unsigned short* pA = stA + spf * ASLOT;
        unsigned short* pB = stB + spf * BSLOT;

        bf16x8 af[4][2];
        #pragma unroll
        for (int mi = 0; mi < 4; ++mi) {
            af[mi][0] = *(const bf16x8*)(sAs + aoff + mi * 1024 + c0);
            af[mi][1] = *(const bf16x8*)(sAs + aoff + mi * 1024 + c1);
        }
        #pragma unroll
        for (int ni = 0; ni < 4; ++ni) {
            bf16x8 b0 = *(const bf16x8*)(sBs + boff + ni * 1024 + c0);
            bf16x8 b1 = *(const bf16x8*)(sBs + boff + ni * 1024 + c1);
            if (kt + 2 < NT) {
                if (ni == 0) {
                    gload_lds16(Ag + gofs,                    pA);
                    gload_lds16(Ag + (size_t) 64 * K + gofs,  pA + 4096);
                } else if (ni == 1) {
                    gload_lds16(Ag + (size_t)128 * K + gofs,  pA + 8192);
                    gload_lds16(Ag + (size_t)192 * K + gofs,  pA + 12288);
                } else if (ni == 2) {
                    gload_lds16(Bg + gofs,                    pB);
                } else {
                    gload_lds16(Bg + (size_t) 64 * K + gofs,  pB + 4096);
                }
            }
            __builtin_amdgcn_s_setprio(1);
            #pragma unroll
            for (int mi = 0; mi < 4; ++mi) {
                acc[mi][ni] = __builtin_amdgcn_mfma_f32_16x16x32_bf16(af[mi][0], b0, acc[mi][ni], 0, 0, 0);
                acc[mi][ni] = __builtin_amdgcn_mfma_f32_16x16x32_bf16(af[mi][1], b1, acc[mi][ni], 0, 0, 0);
            }
            __builtin_amdgcn_s_setprio(0);
        }
        if (kt + 2 < NT)      asm volatile("s_waitcnt vmcnt(6)\ns_barrier" ::: "memory");
        else if (kt + 1 < NT) asm volatile("s_waitcnt vmcnt(0)\ns_barrier" ::: "memory");
        s = (s == 2) ? 0 : s + 1;
    }

    // fused scatter epilogue
    #pragma unroll
    for (int mi = 0; mi < 4; ++mi) {
        #pragma unroll
        for (int j = 0; j < 4; ++j) {
            int row = m0 + wm * 64 + mi * 16 + q * 4 + j;
            int slot = outslot[row];
            if (slot >= 0) {
                float* orow = outF + (size_t)slot * H_;
                const float* prow = ptab + (size_t)posC[row] * H_;
                #pragma unroll
                for (int ni = 0; ni < 4; ++ni) {
                    int col = n0 + wn * 64 + ni * 16 + r16;
                    orow[col] = acc[mi][ni][j] + bias[col] + prow[col];
                }
            }
        }
    }
}

// ---------------------------------------------------------------------------
// K3: per-batch boundary + cumsum + inverse map + compact maps.
// Prefix of lengths computed in-block (wave-0 reduce); block B-1 writes V
// and pads outslot[V..V+256) = -1.
// ---------------------------------------------------------------------------
__global__ __launch_bounds__(512) void scan_scatter_kernel(
    const int* __restrict__ gid, const int* __restrict__ lengths,
    int* __restrict__ idx_map, int* __restrict__ shiftb,
    int* __restrict__ row_id, int* __restrict__ outslot,
    int* __restrict__ posC, int* __restrict__ Vdev)
{
    int b = blockIdx.x, i = threadIdx.x;
    __shared__ int slen[128];
    __shared__ int sres[2];
    if (i < 128) slen[i] = lengths[i];
    __syncthreads();
    if (i < 64) {
        int vpart = (i < b ? slen[i] : 0) + (i + 64 < b ? slen[i + 64] : 0);
        int vall  = slen[i] + slen[i + 64];
        #pragma unroll
        for (int off = 32; off > 0; off >>= 1) {
            vpart += __shfl_xor(vpart, off);
            vall  += __shfl_xor(vall,  off);
        }
        if (i == 0) { sres[0] = vpart; sres[1] = vall; }
    }
    int len = lengths[b];
    int g  = gid[b * L_ + i];
    int gn = (i < L_ - 1) ? gid[b * L_ + i + 1] : g;
    int bnd = (i < len - 1 && g != gn) ? 1 : 0;
    __shared__ int sc[512];
    sc[i] = bnd;
    __syncthreads();
    for (int off = 1; off < 512; off <<= 1) {
        int v = (i >= off) ? sc[i - off] : 0;
        __syncthreads();
        sc[i] += v;
        __syncthreads();
    }
    int incl  = sc[i];
    int total = sc[511];
    int ex = incl - bnd;
    int M = len + total;
    int shift = S_ - M;          // always >= 0
    int pb = sres[0], V = sres[1];
    for (int s = i; s < S_; s += 512) idx_map[b * S_ + s] = -1;
    __syncthreads();
    if (i < len) {
        int p = shift + i + ex;
        idx_map[b * S_ + p] = i;
        if (bnd) idx_map[b * S_ + p + 1] = -2;
        int j = pb + i;
        row_id[j]  = b * L_ + i;
        outslot[j] = b * S_ + p;
        posC[j]    = p;
    }
    if (i == 0) shiftb[b] = shift;
    if (b == B_ - 1) {
        if (i == 0) *Vdev = V;
        if (i < 256) outslot[V + i] = -1;
    }
}

// ---------------------------------------------------------------------------
// K4: fill non-event slots: zeros (s<shift), sep slots, and the mask plane.
// ---------------------------------------------------------------------------
__global__ __launch_bounds__(256) void fill_kernel(
    const int* __restrict__ idx_map, const int* __restrict__ shiftb,
    const float* __restrict__ ptab, const float* __restrict__ sep,
    float* __restrict__ out)
{
    int b = blockIdx.y;
    int s = blockIdx.x * 4 + (threadIdx.x >> 6);
    if (s >= S_) return;
    int h = (threadIdx.x & 63) * 4;
    int shift = shiftb[b];
    float* orow = out + ((size_t)b * S_ + s) * H_;
    if (s < shift) {
        *(f32x4*)(orow + h) = (f32x4)0.0f;
    } else {
        int idx = idx_map[b * S_ + s];
        if (idx == -2) {
            f32x4 pv = *(const f32x4*)(ptab + (size_t)s * H_ + h);
            f32x4 sv = *(const f32x4*)(sep + h);
            *(f32x4*)(orow + h) = pv + sv;
        }
    }
    if ((threadIdx.x & 63) == 0)
        out[(size_t)B_ * S_ * H_ + (size_t)b * S_ + s] = (s >= shift) ? 1.0f : 0.0f;
}

// ---------------------------------------------------------------------------
extern "C" void kernel_launch(void* const* d_in, const int* in_sizes, int n_in,
                              void* d_out, int out_size, void* d_ws, size_t ws_size,
                              hipStream_t stream)
{
    const int*   tok   = (const int*)d_in[0];
    const int*   ptok  = (const int*)d_in[1];
    const int*   atok  = (const int*)d_in[2];
    const int*   actok = (const int*)d_in[3];
    const int*   tgap  = (const int*)d_in[4];
    const int*   gid   = (const int*)d_in[5];
    const int*   lens  = (const int*)d_in[6];
    const float* ttab  = (const float*)d_in[7];
    const float* titab = (const float*)d_in[8];
    const float* gtab  = (const float*)d_in[9];
    const float* post  = (const float*)d_in[10];
    const float* sep   = (const float*)d_in[11];
    const float* gamma = (const float*)d_in[12];
    const float* beta  = (const float*)d_in[13];
    const float* W1    = (const float*)d_in[14];
    const float* b1    = (const float*)d_in[15];
    const float* W2    = (const float*)d_in[16];
    const float* b2    = (const float*)d_in[17];

    unsigned short* xln  = (unsigned short*)d_ws;                 // BL*1536 bf16
    unsigned short* hbuf = xln  + (size_t)BL_ * SIXH;             // BL*1024 bf16
    unsigned short* W1T  = hbuf + (size_t)BL_ * FOURH;            // 1024*1536 bf16
    unsigned short* W2T  = W1T  + (size_t)FOURH * SIXH;           // 256*1024 bf16
    int* idx_map = (int*)(W2T + (size_t)H_ * FOURH);              // B*S int
    int* shiftb  = idx_map + B_ * S_;                             // B
    int* Vdev    = shiftb + B_;                                   // 1 (+pad)
    int* row_id  = Vdev + 4;                                      // BL
    int* outslot = row_id + BL_;                                  // BL+256
    int* posC    = outslot + BL_ + 256;                           // BL
    float* out   = (float*)d_out;

    constexpr int LDS1 = 2 * 32768 * 2;                           // 131072
    constexpr int LDS2 = 3 * (256 * 64 + 128 * 64) * 2;           // 147456
    (void)hipFuncSetAttribute((const void*)&gemm1_kernel,
                              hipFuncAttributeMaxDynamicSharedMemorySize, LDS1);
    (void)hipFuncSetAttribute((const void*)&gemm2_kernel,
                              hipFuncAttributeMaxDynamicSharedMemorySize, LDS2);

    // weight transposes (independent)
    transpose_bf16_kernel<<<dim3(SIXH / 32, FOURH / 32), 256, 0, stream>>>(W1, W1T, SIXH, FOURH);
    transpose_bf16_kernel<<<dim3(FOURH / 32, H_ / 32),   256, 0, stream>>>(W2, W2T, FOURH, H_);

    // scan + prefix + compact maps + V + pad
    scan_scatter_kernel<<<B_, 512, 0, stream>>>(gid, lens, idx_map, shiftb,
                                                row_id, outslot, posC, Vdev);

    // compacted embed + layernorm
    embed_ln_kernel<<<BL_ / 4, 256, 0, stream>>>(tok, ptok, atok, actok, tgap, gid,
                                                 ttab, titab, gtab, gamma, beta,
                                                 row_id, Vdev, xln);

    // MLP over compacted rows
    gemm1_kernel<<<512, 512, LDS1, stream>>>(xln, W1T, b1, hbuf, Vdev);
    gemm2_kernel<<<512, 512, LDS2, stream>>>(hbuf, W2T, b2, outslot, posC, post, out, Vdev);

    // fill zeros / sep slots / mask plane
    fill_kernel<<<dim3((S_ + 3) / 4, B_), 256, 0, stream>>>(idx_map, shiftb, post, sep, out);
}

// Round 10
// 273.284 us; speedup vs baseline: 1.7233x; 1.0335x over previous
//
#include <hip/hip_runtime.h>

#define B_    128
#define L_    512
#define H_    256
#define TGB_  128
#define S_    1023
#define BL_   (B_ * L_)     // 65536
#define SIXH  1536
#define FOURH 1024

typedef __bf16 bf16_t;
typedef bf16_t bf16x8 __attribute__((ext_vector_type(8)));
typedef float  f32x4  __attribute__((ext_vector_type(4)));
typedef unsigned short u16x4 __attribute__((ext_vector_type(4)));

template<int P> struct IC { static constexpr int v = P; };

__device__ __forceinline__ unsigned short f2bf(float f) {
    union { float f; unsigned u; } v; v.f = f;
    unsigned u = v.u;
    unsigned r = u + 0x7FFFu + ((u >> 16) & 1u);   // round-to-nearest-even
    return (unsigned short)(r >> 16);
}

__device__ __forceinline__ void gload_lds16(const void* g, void* l) {
    __builtin_amdgcn_global_load_lds(
        (__attribute__((address_space(1))) void*)(void*)(g),
        (__attribute__((address_space(3))) void*)(l), 16, 0, 0);
}

// ---------------------------------------------------------------------------
// K0: transpose + f32->bf16 convert:  in (R x C) f32  ->  out (C x R) bf16
// ---------------------------------------------------------------------------
__global__ __launch_bounds__(256) void transpose_bf16_kernel(
    const float* __restrict__ in, unsigned short* __restrict__ out,
    int R, int C)
{
    __shared__ float tile[32][33];
    int rb = blockIdx.x * 32, cb = blockIdx.y * 32;
    int tx = threadIdx.x & 31, ty = threadIdx.x >> 5;   // 32 x 8
    #pragma unroll
    for (int d = 0; d < 32; d += 8)
        tile[ty + d][tx] = in[(size_t)(rb + ty + d) * C + cb + tx];
    __syncthreads();
    #pragma unroll
    for (int d = 0; d < 32; d += 8)
        out[(size_t)(cb + ty + d) * R + rb + tx] = f2bf(tile[tx][ty + d]);
}

// ---------------------------------------------------------------------------
// K1: compacted gather + LayerNorm. One wave per valid event j.
// ---------------------------------------------------------------------------
__global__ __launch_bounds__(256) void embed_ln_kernel(
    const int* __restrict__ tok,  const int* __restrict__ ptok,
    const int* __restrict__ atok, const int* __restrict__ actok,
    const int* __restrict__ tgap, const int* __restrict__ gid,
    const float* __restrict__ ttab, const float* __restrict__ titab,
    const float* __restrict__ gtab, const float* __restrict__ gamma,
    const float* __restrict__ beta, const int* __restrict__ row_id,
    const int* __restrict__ Vdev, unsigned short* __restrict__ xln)
{
    int j = blockIdx.x * 4 + (threadIdx.x >> 6);
    if (j >= *Vdev) return;
    int l = threadIdx.x & 63;
    int rid = row_id[j];
    int i0 = tok[rid], i1 = ptok[rid], i2 = atok[rid], i3 = actok[rid];
    int i4 = tgap[rid]; i4 = i4 < 0 ? 0 : (i4 > TGB_ ? TGB_ : i4);
    int i5 = gid[rid];
    f32x4 v[6];
    v[0] = *(const f32x4*)(ttab  + (size_t)i0 * H_ + l * 4);
    v[1] = *(const f32x4*)(ttab  + (size_t)i1 * H_ + l * 4);
    v[2] = *(const f32x4*)(ttab  + (size_t)i2 * H_ + l * 4);
    v[3] = *(const f32x4*)(ttab  + (size_t)i3 * H_ + l * 4);
    v[4] = *(const f32x4*)(titab + (size_t)i4 * H_ + l * 4);
    v[5] = *(const f32x4*)(gtab  + (size_t)i5 * H_ + l * 4);
    float s = 0.0f, sq = 0.0f;
    #pragma unroll
    for (int k = 0; k < 6; ++k)
        #pragma unroll
        for (int c = 0; c < 4; ++c) { float f = v[k][c]; s += f; sq += f * f; }
    #pragma unroll
    for (int off = 32; off > 0; off >>= 1) {
        s  += __shfl_xor(s,  off);
        sq += __shfl_xor(sq, off);
    }
    float mean = s * (1.0f / 1536.0f);
    float var  = sq * (1.0f / 1536.0f) - mean * mean;
    float rstd = rsqrtf(var + 1e-5f);
    unsigned short* orow = xln + (size_t)j * SIXH;
    #pragma unroll
    for (int k = 0; k < 6; ++k) {
        f32x4 g = *(const f32x4*)(gamma + k * H_ + l * 4);
        f32x4 b = *(const f32x4*)(beta  + k * H_ + l * 4);
        u16x4 o;
        #pragma unroll
        for (int c = 0; c < 4; ++c)
            o[c] = f2bf((v[k][c] - mean) * rstd * g[c] + b[c]);
        *(u16x4*)(orow + k * H_ + l * 4) = o;
    }
}

// ---------------------------------------------------------------------------
// K2: 8-phase 128x128 bf16 MFMA GEMM (r6 skeleton, halved tile, 2 blocks/CU).
// 256 threads = 4 waves (2m x 2n), per-wave C = 64x64, 16x16x32 MFMA.
// LDS 64 KiB: 2 bufs x { A[2 kh][128r][32c], B[...] }.  ST2 = 2 gload_lds
// per phase (unit structure identical to r6; vmcnt(4) at P3/P7, RAW/WAR
// ledger isomorphic).  Persistent grid 512 (2 blocks/CU resident),
// m204 bijective XCD swizzle over nact tiles.
// EPI 0: silu -> bf16 C (N=NTN*128).  EPI 2: fused scatter to out f32.
// ---------------------------------------------------------------------------
template<int K, int NTN, int EPI>
__global__ __launch_bounds__(256, 2) void gemm128_kernel(
    const unsigned short* __restrict__ A,
    const unsigned short* __restrict__ Bt,
    const float* __restrict__ bias,
    unsigned short* __restrict__ C,
    const int* __restrict__ outslot,
    const int* __restrict__ posC,
    const float* __restrict__ ptab,
    float* __restrict__ outF,
    const int* __restrict__ Vdev)
{
    constexpr int N = NTN * 128;
    constexpr int NT = K / 64;        // K-tiles
    constexpr int IT = NT / 2;        // 2 K-tiles per iteration
    extern __shared__ __align__(16) unsigned short lds[];   // 32768 shorts

    const int V = *Vdev;
    const int nact = ((V + 127) >> 7) * NTN;
    const int q = nact >> 3, r = nact & 7;

    const int t = threadIdx.x;
    const int w = t >> 6, l = t & 63;
    const int wm = w >> 1, wn = w & 1;
    const int r16 = l & 15, ql = l >> 4;
    const int sg = (t & 3) ^ ((t >> 3) & 3);
    unsigned short* ldsb = lds + w * 512;              // wave-uniform dest base
    const int fr = (ql ^ ((r16 >> 1) & 3)) * 8;

    // fragment read bases (shorts): buf stride 16384; B at +8192
    const unsigned short* la0 = lds + (wm * 64 + r16) * 32 + fr;
    const unsigned short* la1 = la0 + 16384;
    const unsigned short* lb0 = lds + 8192 + (wn * 64 + r16) * 32 + fr;
    const unsigned short* lb1 = lb0 + 16384;

    for (int bidv = blockIdx.x; bidv < nact; bidv += 512) {
        // m204 bijective XCD swizzle
        const int x = bidv & 7, o = bidv >> 3;
        const int wid = (x < r ? x * (q + 1) : r * (q + 1) + (x - r) * q) + o;
        const int mt  = wid / NTN;
        const int m0  = mt * 128;
        const int n0  = (wid - mt * NTN) * 128;

        const unsigned short* As0 = A  + (size_t)(m0 + (t >> 2)) * K + sg * 8;
        const unsigned short* As1 = As0 + (size_t)64 * K;
        const unsigned short* Bs0 = Bt + (size_t)(n0 + (t >> 2)) * K + sg * 8;
        const unsigned short* Bs1 = Bs0 + (size_t)64 * K;

        f32x4 acc[4][4];
        #pragma unroll
        for (int i = 0; i < 4; ++i)
            #pragma unroll
            for (int j = 0; j < 4; ++j) acc[i][j] = (f32x4)0.0f;

        auto ST2 = [&](const unsigned short* s0, const unsigned short* s1,
                       int dofs, int gofs) {
            gload_lds16(s0 + gofs, ldsb + dofs);
            gload_lds16(s1 + gofs, ldsb + dofs + 2048);
        };

        if (bidv != (int)blockIdx.x) __syncthreads();   // LDS WAR guard

        // prologue: units 0..5 (kt0 full, kt1 kh0)
        ST2(As0, As1, 0,     0);    // u0 buf0 A kh0
        ST2(Bs0, Bs1, 8192,  0);    // u1 buf0 B kh0
        ST2(As0, As1, 4096,  32);   // u2 buf0 A kh1
        ST2(Bs0, Bs1, 12288, 32);   // u3 buf0 B kh1
        ST2(As0, As1, 16384, 64);   // u4 buf1 A kh0
        ST2(Bs0, Bs1, 24576, 64);   // u5 buf1 B kh0
        asm volatile("s_waitcnt vmcnt(4)\ns_barrier" ::: "memory");

        bf16x8 bq[4];

        auto phase = [&](auto pc, bool last) {
            constexpr int P   = decltype(pc)::v;
            constexpr int BUF = P >> 2;
            constexpr int KK  = (P & 3) >> 1;
            constexpr int MH  = P & 1;
            const unsigned short* ab = (BUF ? la1 : la0) + KK * 4096 + MH * 1024;
            bf16x8 aq[2];
            if constexpr (MH == 0) {
                const unsigned short* bb = (BUF ? lb1 : lb0) + KK * 4096;
                bq[0] = *(const bf16x8*)(bb);
                bq[1] = *(const bf16x8*)(bb + 512);
                bq[2] = *(const bf16x8*)(bb + 1024);
                bq[3] = *(const bf16x8*)(bb + 1536);
            }
            aq[0] = *(const bf16x8*)(ab);
            aq[1] = *(const bf16x8*)(ab + 512);
            // staging: unit u = 8it+6+P (ledger isomorphic to r6)
            if constexpr (P == 0)      {            ST2(As0, As1, 20480, 96);  }
            else if constexpr (P == 1) {            ST2(Bs0, Bs1, 28672, 96);  }
            else if constexpr (P == 2) { if (!last) ST2(As0, As1, 0,     128); }
            else if constexpr (P == 3) { if (!last) ST2(Bs0, Bs1, 8192,  128); }
            else if constexpr (P == 4) { if (!last) ST2(As0, As1, 4096,  160); }
            else if constexpr (P == 5) { if (!last) ST2(Bs0, Bs1, 12288, 160); }
            else if constexpr (P == 6) { if (!last) ST2(As0, As1, 16384, 192); }
            else                       { if (!last) ST2(Bs0, Bs1, 24576, 192); }
            asm volatile("s_barrier" ::: "memory");
            __builtin_amdgcn_s_setprio(1);
            #pragma unroll
            for (int mm = 0; mm < 2; ++mm)
                #pragma unroll
                for (int nn = 0; nn < 4; ++nn)
                    acc[MH * 2 + mm][nn] = __builtin_amdgcn_mfma_f32_16x16x32_bf16(
                        aq[mm], bq[nn], acc[MH * 2 + mm][nn], 0, 0, 0);
            __builtin_amdgcn_s_setprio(0);
            if constexpr (P == 3) {
                if (last) asm volatile("s_waitcnt vmcnt(0)\ns_barrier" ::: "memory");
                else      asm volatile("s_waitcnt vmcnt(4)\ns_barrier" ::: "memory");
            } else if constexpr (P == 7) {
                if (!last) asm volatile("s_waitcnt vmcnt(4)\ns_barrier" ::: "memory");
            } else {
                asm volatile("s_barrier" ::: "memory");
            }
        };

        for (int it = 0; it < IT; ++it) {
            const bool last = (it == IT - 1);
            phase(IC<0>{}, last);
            phase(IC<1>{}, last);
            phase(IC<2>{}, last);
            phase(IC<3>{}, last);
            phase(IC<4>{}, last);
            phase(IC<5>{}, last);
            phase(IC<6>{}, last);
            phase(IC<7>{}, last);
            As0 += 128; As1 += 128; Bs0 += 128; Bs1 += 128;
        }

        if constexpr (EPI == 0) {
            #pragma unroll
            for (int mi = 0; mi < 4; ++mi) {
                #pragma unroll
                for (int ni = 0; ni < 4; ++ni) {
                    int col = n0 + wn * 64 + ni * 16 + r16;
                    float bv = bias[col];
                    #pragma unroll
                    for (int j = 0; j < 4; ++j) {
                        int row = m0 + wm * 64 + mi * 16 + ql * 4 + j;
                        float v = acc[mi][ni][j] + bv;
                        v = v / (1.0f + __expf(-v));   // silu
                        C[(size_t)row * N + col] = f2bf(v);
                    }
                }
            }
        } else {
            // fused scatter: compact row -> out slot, + bias + pos_table
            #pragma unroll
            for (int mi = 0; mi < 4; ++mi) {
                #pragma unroll
                for (int j = 0; j < 4; ++j) {
                    int row = m0 + wm * 64 + mi * 16 + ql * 4 + j;
                    int slot = outslot[row];
                    if (slot >= 0) {
                        float* orow = outF + (size_t)slot * H_;
                        const float* prow = ptab + (size_t)posC[row] * H_;
                        #pragma unroll
                        for (int ni = 0; ni < 4; ++ni) {
                            int col = n0 + wn * 64 + ni * 16 + r16;
                            orow[col] = acc[mi][ni][j] + bias[col] + prow[col];
                        }
                    }
                }
            }
        }
    }
}

// ---------------------------------------------------------------------------
// K3: per-batch boundary + cumsum + inverse map + compact maps.
// Prefix computed in-block; block B-1 writes V and pads outslot[V..V+256)=-1.
// ---------------------------------------------------------------------------
__global__ __launch_bounds__(512) void scan_scatter_kernel(
    const int* __restrict__ gid, const int* __restrict__ lengths,
    int* __restrict__ idx_map, int* __restrict__ shiftb,
    int* __restrict__ row_id, int* __restrict__ outslot,
    int* __restrict__ posC, int* __restrict__ Vdev)
{
    int b = blockIdx.x, i = threadIdx.x;
    __shared__ int slen[128];
    __shared__ int sres[2];
    if (i < 128) slen[i] = lengths[i];
    __syncthreads();
    if (i < 64) {
        int vpart = (i < b ? slen[i] : 0) + (i + 64 < b ? slen[i + 64] : 0);
        int vall  = slen[i] + slen[i + 64];
        #pragma unroll
        for (int off = 32; off > 0; off >>= 1) {
            vpart += __shfl_xor(vpart, off);
            vall  += __shfl_xor(vall,  off);
        }
        if (i == 0) { sres[0] = vpart; sres[1] = vall; }
    }
    int len = lengths[b];
    int g  = gid[b * L_ + i];
    int gn = (i < L_ - 1) ? gid[b * L_ + i + 1] : g;
    int bnd = (i < len - 1 && g != gn) ? 1 : 0;
    __shared__ int sc[512];
    sc[i] = bnd;
    __syncthreads();
    for (int off = 1; off < 512; off <<= 1) {
        int v = (i >= off) ? sc[i - off] : 0;
        __syncthreads();
        sc[i] += v;
        __syncthreads();
    }
    int incl  = sc[i];
    int total = sc[511];
    int ex = incl - bnd;
    int M = len + total;
    int shift = S_ - M;          // always >= 0
    int pb = sres[0], V = sres[1];
    for (int s = i; s < S_; s += 512) idx_map[b * S_ + s] = -1;
    __syncthreads();
    if (i < len) {
        int p = shift + i + ex;
        idx_map[b * S_ + p] = i;
        if (bnd) idx_map[b * S_ + p + 1] = -2;
        int j = pb + i;
        row_id[j]  = b * L_ + i;
        outslot[j] = b * S_ + p;
        posC[j]    = p;
    }
    if (i == 0) shiftb[b] = shift;
    if (b == B_ - 1) {
        if (i == 0) *Vdev = V;
        if (i < 256) outslot[V + i] = -1;
    }
}

// ---------------------------------------------------------------------------
// K4: fill non-event slots: zeros (s<shift), sep slots, and the mask plane.
// ---------------------------------------------------------------------------
__global__ __launch_bounds__(256) void fill_kernel(
    const int* __restrict__ idx_map, const int* __restrict__ shiftb,
    const float* __restrict__ ptab, const float* __restrict__ sep,
    float* __restrict__ out)
{
    int b = blockIdx.y;
    int s = blockIdx.x * 4 + (threadIdx.x >> 6);
    if (s >= S_) return;
    int h = (threadIdx.x & 63) * 4;
    int shift = shiftb[b];
    float* orow = out + ((size_t)b * S_ + s) * H_;
    if (s < shift) {
        *(f32x4*)(orow + h) = (f32x4)0.0f;
    } else {
        int idx = idx_map[b * S_ + s];
        if (idx == -2) {
            f32x4 pv = *(const f32x4*)(ptab + (size_t)s * H_ + h);
            f32x4 sv = *(const f32x4*)(sep + h);
            *(f32x4*)(orow + h) = pv + sv;
        }
    }
    if ((threadIdx.x & 63) == 0)
        out[(size_t)B_ * S_ * H_ + (size_t)b * S_ + s] = (s >= shift) ? 1.0f : 0.0f;
}

// ---------------------------------------------------------------------------
extern "C" void kernel_launch(void* const* d_in, const int* in_sizes, int n_in,
                              void* d_out, int out_size, void* d_ws, size_t ws_size,
                              hipStream_t stream)
{
    const int*   tok   = (const int*)d_in[0];
    const int*   ptok  = (const int*)d_in[1];
    const int*   atok  = (const int*)d_in[2];
    const int*   actok = (const int*)d_in[3];
    const int*   tgap  = (const int*)d_in[4];
    const int*   gid   = (const int*)d_in[5];
    const int*   lens  = (const int*)d_in[6];
    const float* ttab  = (const float*)d_in[7];
    const float* titab = (const float*)d_in[8];
    const float* gtab  = (const float*)d_in[9];
    const float* post  = (const float*)d_in[10];
    const float* sep   = (const float*)d_in[11];
    const float* gamma = (const float*)d_in[12];
    const float* beta  = (const float*)d_in[13];
    const float* W1    = (const float*)d_in[14];
    const float* b1    = (const float*)d_in[15];
    const float* W2    = (const float*)d_in[16];
    const float* b2    = (const float*)d_in[17];

    unsigned short* xln  = (unsigned short*)d_ws;                 // BL*1536 bf16
    unsigned short* hbuf = xln  + (size_t)BL_ * SIXH;             // BL*1024 bf16
    unsigned short* W1T  = hbuf + (size_t)BL_ * FOURH;            // 1024*1536 bf16
    unsigned short* W2T  = W1T  + (size_t)FOURH * SIXH;           // 256*1024 bf16
    int* idx_map = (int*)(W2T + (size_t)H_ * FOURH);              // B*S int
    int* shiftb  = idx_map + B_ * S_;                             // B
    int* Vdev    = shiftb + B_;                                   // 1 (+pad)
    int* row_id  = Vdev + 4;                                      // BL
    int* outslot = row_id + BL_;                                  // BL+256
    int* posC    = outslot + BL_ + 256;                           // BL
    float* out   = (float*)d_out;

    constexpr int LDSG = 2 * 16384 * 2;                           // 65536
    (void)hipFuncSetAttribute((const void*)&gemm128_kernel<SIXH, 8, 0>,
                              hipFuncAttributeMaxDynamicSharedMemorySize, LDSG);
    (void)hipFuncSetAttribute((const void*)&gemm128_kernel<FOURH, 2, 2>,
                              hipFuncAttributeMaxDynamicSharedMemorySize, LDSG);

    // weight transposes (independent)
    transpose_bf16_kernel<<<dim3(SIXH / 32, FOURH / 32), 256, 0, stream>>>(W1, W1T, SIXH, FOURH);
    transpose_bf16_kernel<<<dim3(FOURH / 32, H_ / 32),   256, 0, stream>>>(W2, W2T, FOURH, H_);

    // scan + prefix + compact maps + V + pad
    scan_scatter_kernel<<<B_, 512, 0, stream>>>(gid, lens, idx_map, shiftb,
                                                row_id, outslot, posC, Vdev);

    // compacted embed + layernorm
    embed_ln_kernel<<<BL_ / 4, 256, 0, stream>>>(tok, ptok, atok, actok, tgap, gid,
                                                 ttab, titab, gtab, gamma, beta,
                                                 row_id, Vdev, xln);

    // MLP over compacted rows (128^2 8-phase, persistent 512, 2 blocks/CU)
    gemm128_kernel<SIXH, 8, 0><<<512, 256, LDSG, stream>>>(
        xln, W1T, b1, hbuf, nullptr, nullptr, nullptr, nullptr, Vdev);
    gemm128_kernel<FOURH, 2, 2><<<512, 256, LDSG, stream>>>(
        hbuf, W2T, b2, nullptr, outslot, posC, post, out, Vdev);

    // fill zeros / sep slots / mask plane
    fill_kernel<<<dim3((S_ + 3) / 4, B_), 256, 0, stream>>>(idx_map, shiftb, post, sep, out);
}